// Round 7
// baseline (848.326 us; speedup 1.0000x reference)
//
#include <hip/hip_runtime.h>
#include <math.h>

// Problem constants
#define B_    8
#define SEQ   1569      // 1 + 196*8
#define DIMX  768
#define H_    12
#define D3    192       // head dim slice (3*DH)
#define F_    8
#define NP    196
#define P1    195       // patches kept per frame
#define NCOL  2304      // 3*DIM
#define NS    6912      // fused QKV row stride (3*NCOL)
#define RSCALE (1.0f/96.0f)
#define NCHUNK 16       // cls split-K chunks
#define CH     99       // keys per chunk (16*99 >= 1569)
#define CLS_STRIDE 196  // 192 o + m + l (+pad)
#define PG4   49        // ceil(P1/4) patch groups for temporal

typedef __bf16 bf16_t;
typedef bf16_t bf16x8 __attribute__((ext_vector_type(8)));
typedef float  f32x4  __attribute__((ext_vector_type(4)));

// async global->LDS, 16B per lane; LDS dest = wave-uniform base + lane*16
__device__ __forceinline__ void load_lds16(const bf16_t* g, bf16_t* l) {
  __builtin_amdgcn_global_load_lds(
      (const __attribute__((address_space(1))) void*)g,
      (__attribute__((address_space(3))) void*)l, 16, 0, 0);
}

// ---------------- block reduction helpers (blockDim == 256) ----------------
__device__ __forceinline__ float block_max256(float v, float* red) {
  #pragma unroll
  for (int o = 32; o > 0; o >>= 1) v = fmaxf(v, __shfl_xor(v, o, 64));
  __syncthreads();
  if ((threadIdx.x & 63) == 0) red[threadIdx.x >> 6] = v;
  __syncthreads();
  return fmaxf(fmaxf(red[0], red[1]), fmaxf(red[2], red[3]));
}

__device__ __forceinline__ float block_sum256(float v, float* red) {
  #pragma unroll
  for (int o = 32; o > 0; o >>= 1) v += __shfl_xor(v, o, 64);
  __syncthreads();
  if ((threadIdx.x & 63) == 0) red[threadIdx.x >> 6] = v;
  __syncthreads();
  return red[0] + red[1] + red[2] + red[3];
}

// ---------------- cast fp32 -> bf16 (vector of 4) ----------------
__global__ __launch_bounds__(256) void cast_f32_bf16(
    const float* __restrict__ in, bf16_t* __restrict__ out, int n4) {
  const int i = blockIdx.x * 256 + threadIdx.x;
  if (i >= n4) return;
  const float4 v = ((const float4*)in)[i];
  bf16_t o4[4] = {(bf16_t)v.x, (bf16_t)v.y, (bf16_t)v.z, (bf16_t)v.w};
  ((uint2*)out)[i] = *(uint2*)o4;
}

// ---------------- concat q/k/v biases ----------------
__global__ __launch_bounds__(256) void concat_bias_kernel(
    const float* __restrict__ bq, const float* __restrict__ bk,
    const float* __restrict__ bv, float* __restrict__ qkvb) {
  const int i = blockIdx.x * 256 + threadIdx.x;
  if (i >= NS) return;
  float v;
  if (i < NCOL) v = bq[i];
  else if (i < 2 * NCOL) v = bk[i - NCOL];
  else v = bv[i - 2 * NCOL];
  qkvb[i] = v;
}

// ---------------- batched transpose+cast of the 5 weight matrices ----------
// grid = 1728 * 5; mats 0-2: 768x2304 -> WqkvT rows; mats 3-4: 2304x768.
__global__ __launch_bounds__(256) void transpose_all(
    const float* __restrict__ Wq, const float* __restrict__ Wk,
    const float* __restrict__ Wv, const float* __restrict__ Wt,
    const float* __restrict__ Wf, bf16_t* __restrict__ WqkvT,
    bf16_t* __restrict__ WtT, bf16_t* __restrict__ WfT) {
  __shared__ float t[32][33];
  const int bid = blockIdx.x;
  const int mat = bid / 1728, tt = bid % 1728;
  const float* W; bf16_t* WT; int Kd, Nd, nt, kt;
  if (mat < 3) {
    Kd = DIMX; Nd = NCOL;
    W = (mat == 0) ? Wq : ((mat == 1) ? Wk : Wv);
    WT = WqkvT + (size_t)mat * NCOL * DIMX;
    nt = tt % 72; kt = tt / 72;
  } else {
    Kd = NCOL; Nd = DIMX;
    W = (mat == 3) ? Wt : Wf;
    WT = (mat == 3) ? WtT : WfT;
    nt = tt % 24; kt = tt / 24;
  }
  const int bn = nt * 32, bk = kt * 32;
  const int tx = threadIdx.x & 31, ty = threadIdx.x >> 5;  // 32 x 8
  #pragma unroll
  for (int i = 0; i < 32; i += 8)
    t[ty + i][tx] = W[(size_t)(bk + ty + i) * Nd + bn + tx];
  __syncthreads();
  #pragma unroll
  for (int i = 0; i < 32; i += 8)
    WT[(size_t)(bn + ty + i) * Kd + bk + tx] = (bf16_t)t[tx][ty + i];
}

// ---------------- bf16 MFMA GEMM: C = A @ BT^T + bias ----------------
// Double-buffered async staging: prefetch k+1 while MFMAs run on k; raw
// s_barrier + manual s_waitcnt vmcnt(4) keeps prefetch in flight across the
// barrier. Fragment-major LDS (zero bank conflicts).
// XCDB>0: grid = 8*XCDB*NT, XCD x owns m-tiles [x*XCDB, (x+1)*XCDB) (A band
// stays in that XCD's L2; B streams via L3). XCDB==0: grouped-m swizzle.
__global__ __launch_bounds__(256) void gemm_mfma_bt(
    const bf16_t* __restrict__ A, const bf16_t* __restrict__ BT,
    const float* __restrict__ bias, void* __restrict__ C,
    int M, int N, int K, int MT, int NT, int GROUPM, int XCDB, int outBf16) {
  __shared__ bf16_t As[2][128 * 32];
  __shared__ bf16_t Bs[2][128 * 32];
  const int tid  = threadIdx.x;
  const int wave = tid >> 6, lane = tid & 63;

  int m_tile, n_tile;
  const int pid = blockIdx.x;
  if (XCDB > 0) {
    const int xcd = pid & 7, q = pid >> 3;
    m_tile = xcd * XCDB + q % XCDB;
    n_tile = q / XCDB;
    if (m_tile >= MT) return;
  } else {
    const int npg   = GROUPM * NT;
    const int group = pid / npg;
    const int first_m = group * GROUPM;
    int gsm = MT - first_m; if (gsm > GROUPM) gsm = GROUPM;
    const int lpid  = pid % npg;
    m_tile = first_m + lpid % gsm;
    n_tile = lpid / gsm;
  }
  const int row0 = m_tile * 128, col0 = n_tile * 128;

  // staging: lane (fr, kg) fetches row fr of a 16-row block, k-seg kg
  const int fr = lane & 15, kg = lane >> 4;
  int ra0 = row0 + wave * 32 + fr;
  int ra1 = ra0 + 16;
  if (ra0 >= M) ra0 = M - 1;
  if (ra1 >= M) ra1 = M - 1;
  const bf16_t* Ap0 = A + (size_t)ra0 * K + kg * 8;
  const bf16_t* Ap1 = A + (size_t)ra1 * K + kg * 8;
  const bf16_t* Bp0 = BT + (size_t)(col0 + wave * 32 + fr) * K + kg * 8;
  const bf16_t* Bp1 = Bp0 + (size_t)16 * K;
  const int la0 = (wave * 2 + 0) * 512, la1 = (wave * 2 + 1) * 512;

  const int m0 = (wave & 1) * 64, n0 = (wave >> 1) * 64;
  const int mb = (wave & 1) * 4,  nb = (wave >> 1) * 4;
  f32x4 acc[4][4] = {};

  const int nk = K >> 5;
  // prologue: stage k=0 into buffer 0
  load_lds16(Ap0, &As[0][la0]);
  load_lds16(Ap1, &As[0][la1]);
  load_lds16(Bp0, &Bs[0][la0]);
  load_lds16(Bp1, &Bs[0][la1]);

  for (int kk = 0; kk < nk; ++kk) {
    const int p = kk & 1;
    if (kk + 1 < nk) {
      const int k0 = (kk + 1) * 32;
      load_lds16(Ap0 + k0, &As[p ^ 1][la0]);
      load_lds16(Ap1 + k0, &As[p ^ 1][la1]);
      load_lds16(Bp0 + k0, &Bs[p ^ 1][la0]);
      load_lds16(Bp1 + k0, &Bs[p ^ 1][la1]);
      __builtin_amdgcn_s_waitcnt(0x0F74);  // vmcnt(4): current buf done, prefetch in flight
    } else {
      __builtin_amdgcn_s_waitcnt(0x0F70);  // vmcnt(0)
    }
    __builtin_amdgcn_s_barrier();

    bf16x8 af[4], bfr[4];
    #pragma unroll
    for (int i = 0; i < 4; ++i) {
      af[i]  = *(const bf16x8*)&As[p][(mb + i) * 512 + lane * 8];
      bfr[i] = *(const bf16x8*)&Bs[p][(nb + i) * 512 + lane * 8];
    }
    #pragma unroll
    for (int i = 0; i < 4; ++i)
      #pragma unroll
      for (int j = 0; j < 4; ++j)
        acc[i][j] = __builtin_amdgcn_mfma_f32_16x16x32_bf16(
            af[i], bfr[j], acc[i][j], 0, 0, 0);
    __builtin_amdgcn_s_barrier();        // all waves done reading buf p
  }

  const int cc = lane & 15, cr4 = (lane >> 4) * 4;
  #pragma unroll
  for (int i = 0; i < 4; ++i) {
    #pragma unroll
    for (int j = 0; j < 4; ++j) {
      const int col = col0 + n0 + j * 16 + cc;
      const float bcol = bias[col];
      #pragma unroll
      for (int reg = 0; reg < 4; ++reg) {
        const int r = row0 + m0 + i * 16 + cr4 + reg;
        if (r < M) {
          const float v = acc[i][j][reg] + bcol;
          if (outBf16) ((bf16_t*)C)[(size_t)r * N + col] = (bf16_t)v;
          else         ((float*)C)[(size_t)r * N + col] = v;
        }
      }
    }
  }
}

// ---------------- xi0 scores via MFMA: S = RSCALE * Q2 @ K2^T per (b,h) ------
// grid (2, 2, 96). Q at QKV2 col 0, K at col 2*NCOL; row stride NS.
__global__ __launch_bounds__(256) void xi0_scores_mfma(
    const bf16_t* __restrict__ QKV2, float* __restrict__ Smat) {
  __shared__ bf16_t As[128 * 32];
  __shared__ bf16_t Bs[128 * 32];
  const int tid  = threadIdx.x;
  const int wave = tid >> 6, lane = tid & 63;
  const int row0 = blockIdx.x * 128, col0 = blockIdx.y * 128;
  const int bh = blockIdx.z;
  const int b = bh / H_, h = bh % H_;
  const bf16_t* Abase = QKV2 + (size_t)b * P1 * NS + h * D3;             // Q2
  const bf16_t* Bbase = QKV2 + (size_t)b * P1 * NS + 2 * NCOL + h * D3;  // K2

  const int fr = lane & 15, kg = lane >> 4;
  int ra0 = row0 + wave * 32 + fr;
  int ra1 = ra0 + 16;
  if (ra0 >= P1) ra0 = P1 - 1;
  if (ra1 >= P1) ra1 = P1 - 1;
  int cb0 = col0 + wave * 32 + fr;
  int cb1 = cb0 + 16;
  if (cb0 >= P1) cb0 = P1 - 1;
  if (cb1 >= P1) cb1 = P1 - 1;
  const bf16_t* Ap0 = Abase + (size_t)ra0 * NS + kg * 8;
  const bf16_t* Ap1 = Abase + (size_t)ra1 * NS + kg * 8;
  const bf16_t* Bp0 = Bbase + (size_t)cb0 * NS + kg * 8;
  const bf16_t* Bp1 = Bbase + (size_t)cb1 * NS + kg * 8;
  bf16_t* lA0 = &As[(wave * 2 + 0) * 512];
  bf16_t* lA1 = &As[(wave * 2 + 1) * 512];
  bf16_t* lB0 = &Bs[(wave * 2 + 0) * 512];
  bf16_t* lB1 = &Bs[(wave * 2 + 1) * 512];

  const int m0 = (wave & 1) * 64, n0 = (wave >> 1) * 64;
  const int mb = (wave & 1) * 4,  nb = (wave >> 1) * 4;
  f32x4 acc[4][4] = {};

  for (int k0 = 0; k0 < D3; k0 += 32) {
    load_lds16(Ap0 + k0, lA0);
    load_lds16(Ap1 + k0, lA1);
    load_lds16(Bp0 + k0, lB0);
    load_lds16(Bp1 + k0, lB1);
    __syncthreads();
    bf16x8 af[4], bfr[4];
    #pragma unroll
    for (int i = 0; i < 4; ++i) {
      af[i]  = *(const bf16x8*)&As[(mb + i) * 512 + lane * 8];
      bfr[i] = *(const bf16x8*)&Bs[(nb + i) * 512 + lane * 8];
    }
    #pragma unroll
    for (int i = 0; i < 4; ++i)
      #pragma unroll
      for (int j = 0; j < 4; ++j)
        acc[i][j] = __builtin_amdgcn_mfma_f32_16x16x32_bf16(
            af[i], bfr[j], acc[i][j], 0, 0, 0);
    __syncthreads();
  }

  float* S = Smat + (size_t)bh * P1 * P1;
  const int cc = lane & 15, cr4 = (lane >> 4) * 4;
  #pragma unroll
  for (int i = 0; i < 4; ++i)
    #pragma unroll
    for (int j = 0; j < 4; ++j) {
      const int col = col0 + n0 + j * 16 + cc;
      #pragma unroll
      for (int reg = 0; reg < 4; ++reg) {
        const int r = row0 + m0 + i * 16 + cr4 + reg;
        if (r < P1 && col < P1) S[(size_t)r * P1 + col] = acc[i][j][reg] * RSCALE;
      }
    }
}

// ---------------- xi0 finish: row softmax stats, colsum, PV ----------------
__global__ __launch_bounds__(256) void xi0_finish_kernel(
    const float* __restrict__ Smat, const bf16_t* __restrict__ QKV2,
    bf16_t* __restrict__ FULL9b) {
  const int bh = blockIdx.x;
  const int b = bh / H_, h = bh % H_;
  __shared__ float mrow[P1], inv_l[P1], g[P1];
  const float* S = Smat + (size_t)bh * P1 * P1;
  const int tid = threadIdx.x;

  if (tid < P1) {
    float m = -1e30f;
    for (int k = 0; k < P1; ++k) m = fmaxf(m, S[(size_t)tid * P1 + k]);
    float l = 0.f;
    for (int k = 0; k < P1; ++k)
      l += expf(S[(size_t)tid * P1 + k] - m) * ((k == 0) ? 2.f : 1.f);
    mrow[tid] = m;
    inv_l[tid] = ((tid == 0) ? 2.f : 1.f) / l;   // query-row multiplicity / denom
  }
  __syncthreads();
  if (tid < P1) {
    float s = 0.f;
    for (int r = 0; r < P1; ++r)
      s += expf(S[(size_t)r * P1 + tid] - mrow[r]) * inv_l[r];
    g[tid] = s * ((tid == 0) ? 2.f : 1.f);       // key-0 multiplicity
  }
  __syncthreads();
  if (tid < D3) {
    float acc = 0.f;
    const bf16_t* vbase = QKV2 + (size_t)b * P1 * NS + NCOL + h * D3 + tid;  // V2
    for (int k = 0; k < P1; ++k)
      acc = fmaf(g[k], (float)vbase[(size_t)k * NS], acc);
    FULL9b[((size_t)b * 9 + 1) * NCOL + h * D3 + tid] = (bf16_t)acc;
  }
}

// ---------------- cls attention, split over keys ----------------
// XQKV row layout: [q | k(Wk) | v(Wv)], stride NS.
__global__ __launch_bounds__(256) void cls_part_kernel(
    const bf16_t* __restrict__ XQKV, float* __restrict__ CLSP, int b0) {
  const int h  = blockIdx.x % H_;
  const int bl = blockIdx.x / H_;
  const int b  = b0 + bl;
  const int c  = blockIdx.y;
  const int t0 = c * CH;
  const int tend = (t0 + CH < SEQ) ? t0 + CH : SEQ;
  __shared__ float qs[D3];
  __shared__ float sc[CH];
  __shared__ float red[4];
  const int tid = threadIdx.x;

  const bf16_t* Qr = XQKV + (size_t)bl * SEQ * NS + h * D3;
  if (tid < 24) {
    const bf16x8 q8 = *(const bf16x8*)(Qr + tid * 8);
    #pragma unroll
    for (int m2 = 0; m2 < 8; ++m2) qs[tid * 8 + m2] = (float)q8[m2];
  }
  __syncthreads();

  float lmax = -1e30f;
  for (int t = t0 + tid; t < tend; t += 256) {
    const bf16_t* kr = XQKV + ((size_t)bl * SEQ + t) * NS + NCOL + h * D3;
    float acc = 0.f;
    #pragma unroll 3
    for (int d = 0; d < D3; d += 8) {
      const bf16x8 k8 = *(const bf16x8*)(kr + d);
      #pragma unroll
      for (int m2 = 0; m2 < 8; ++m2) acc = fmaf(qs[d + m2], (float)k8[m2], acc);
    }
    acc *= RSCALE;
    sc[t - t0] = acc;
    lmax = fmaxf(lmax, acc);
  }
  const float m = block_max256(lmax, red);
  float lsum = 0.f;
  for (int t = t0 + tid; t < tend; t += 256) {
    const float e = expf(sc[t - t0] - m);
    sc[t - t0] = e;
    lsum += e;
  }
  const float L = block_sum256(lsum, red);
  __syncthreads();

  float* P = CLSP + ((size_t)(b * H_ + h) * NCHUNK + c) * CLS_STRIDE;
  if (tid < D3) {
    float acc = 0.f;
    const bf16_t* vbase = XQKV + ((size_t)bl * SEQ + t0) * NS + 2 * NCOL + h * D3 + tid;
    for (int t = t0; t < tend; ++t)
      acc = fmaf(sc[t - t0], (float)vbase[(size_t)(t - t0) * NS], acc);
    P[tid] = acc;
  }
  if (tid == 192) P[192] = m;
  if (tid == 193) P[193] = L;
}

// ---------------- cls combine: merge NCHUNK partials ----------------
__global__ __launch_bounds__(256) void cls_combine_kernel(
    const float* __restrict__ CLSP, bf16_t* __restrict__ FULL9b) {
  const int bh = blockIdx.x;
  const int tid = threadIdx.x;
  const float* P = CLSP + (size_t)bh * NCHUNK * CLS_STRIDE;

  float M = -1e30f;
  #pragma unroll
  for (int c = 0; c < NCHUNK; ++c) M = fmaxf(M, P[c * CLS_STRIDE + 192]);
  float L = 0.f;
  float w[NCHUNK];
  #pragma unroll
  for (int c = 0; c < NCHUNK; ++c) {
    w[c] = expf(P[c * CLS_STRIDE + 192] - M);
    L += P[c * CLS_STRIDE + 193] * w[c];
  }
  if (tid < D3) {
    float acc = 0.f;
    #pragma unroll
    for (int c = 0; c < NCHUNK; ++c)
      acc = fmaf(w[c], P[c * CLS_STRIDE + tid], acc);
    const int b = bh / H_, h = bh % H_;
    FULL9b[((size_t)b * 9 + 0) * NCOL + h * D3 + tid] = (bf16_t)(acc / L);
  }
}

// ---------------- temporal attention, 4 patches (waves) per block ----------
// q col 0, k col 2*NCOL (Wv proj!), v col NCOL (Wk proj!).
__global__ __launch_bounds__(256) void temporal_kernel(
    const bf16_t* __restrict__ XQKV, bf16_t* __restrict__ T1U, int b0) {
  const int id = blockIdx.x;
  const int pg = id % PG4;
  const int h  = (id / PG4) % H_;
  const int bl = id / (PG4 * H_);
  const int b  = b0 + bl;
  const int wave = threadIdx.x >> 6, lane = threadIdx.x & 63;
  __shared__ float qs[4][8][196], ks[4][8][196];

  int pi = pg * 4 + wave;
  const bool act = (pi < P1);
  if (!act) pi = P1 - 1;

  #pragma unroll
  for (int i = 0; i < 6; ++i) {
    const int idx = lane + 64 * i;  // 0..383: [0,192) -> qs, [192,384) -> ks
    const int arr = idx / 192;
    const int c = idx % 192;        // chunk of 8 dims
    const int f = c / 24, d0 = (c % 24) * 8;
    const size_t base = ((size_t)bl * SEQ + (size_t)f * NP + pi + 2) * NS +
                        (arr ? 2 * NCOL : 0) + h * D3 + d0;
    const bf16x8 v8 = *(const bf16x8*)(XQKV + base);
    float* dst = arr ? &ks[wave][f][d0] : &qs[wave][f][d0];
    #pragma unroll
    for (int m2 = 0; m2 < 8; ++m2) dst[m2] = (float)v8[m2];
  }
  __syncthreads();

  const int f = lane >> 3, g = lane & 7;
  float s = 0.f;
  for (int d = 0; d < D3; d += 4) {
    const float4 a4 = *(const float4*)&qs[wave][f][d];
    const float4 b4 = *(const float4*)&ks[wave][g][d];
    s = fmaf(a4.x, b4.x, s); s = fmaf(a4.y, b4.y, s);
    s = fmaf(a4.z, b4.z, s); s = fmaf(a4.w, b4.w, s);
  }
  s *= RSCALE;

  float m = s;
  #pragma unroll
  for (int o = 1; o < 8; o <<= 1) m = fmaxf(m, __shfl_xor(m, o, 64));
  const float e = expf(s - m);
  float sum = e;
  #pragma unroll
  for (int o = 1; o < 8; o <<= 1) sum += __shfl_xor(sum, o, 64);
  float a = e / sum;
  #pragma unroll
  for (int o = 8; o < 64; o <<= 1) a += __shfl_xor(a, o, 64);  // column sums
  float wg[8];
  #pragma unroll
  for (int gg = 0; gg < 8; ++gg) wg[gg] = __shfl(a, gg, 64);

  if (act) {
    const size_t vrow = (size_t)bl * SEQ * NS + NCOL + h * D3;  // values: Wk proj
    #pragma unroll
    for (int i = 0; i < 3; ++i) {
      const int d = lane + 64 * i;
      float o = 0.f;
      #pragma unroll
      for (int gg = 0; gg < 8; ++gg) {
        const bf16_t vv = XQKV[vrow + ((size_t)gg * NP + pi + 2) * NS + d];
        o = fmaf(wg[gg], (float)vv, o);
      }
      T1U[((size_t)b * P1 + pi) * NCOL + h * D3 + d] = (bf16_t)o;
    }
  }
}

// ---------------- stage-2, xi = 1..7: 195(+dup row xi) queries over 8 keys ----
// QKV2 layout: [q2 | v2(Wk) | k2(Wv)], stride NS.
__global__ __launch_bounds__(256) void stage2_xi_kernel(
    const bf16_t* __restrict__ QKV2, bf16_t* __restrict__ FULL9b) {
  const int xi = 1 + blockIdx.x % 7;
  const int h  = (blockIdx.x / 7) % H_;
  const int b  = blockIdx.x / (7 * H_);
  __shared__ float Ks[8][196], Vs[8][196], Qs[32][196];
  __shared__ float Pp[32][8];
  const int tid = threadIdx.x;

  for (int idx = tid; idx < 192; idx += 256) {          // keys: col 2*NCOL
    const int k = idx / 24, d0 = (idx % 24) * 8;
    const bf16x8 v8 = *(const bf16x8*)(QKV2 + ((size_t)(b * P1 + xi + k)) * NS +
                                       2 * NCOL + h * D3 + d0);
    #pragma unroll
    for (int m2 = 0; m2 < 8; ++m2) Ks[k][d0 + m2] = (float)v8[m2];
  }
  for (int idx = tid; idx < 192; idx += 256) {          // values: col NCOL
    const int k = idx / 24, d0 = (idx % 24) * 8;
    const bf16x8 v8 = *(const bf16x8*)(QKV2 + ((size_t)(b * P1 + xi + k)) * NS +
                                       NCOL + h * D3 + d0);
    #pragma unroll
    for (int m2 = 0; m2 < 8; ++m2) Vs[k][d0 + m2] = (float)v8[m2];
  }

  float acc = 0.f;  // for d = tid (tid < 192)
  for (int c = 0; c < 7; ++c) {
    __syncthreads();
    for (int idx = tid; idx < 768; idx += 256) {        // 32 queries x 192 dims
      const int qr = idx / 24, d0 = (idx % 24) * 8;
      const int rq = c * 32 + qr;
      if (rq < P1) {
        const bf16x8 v8 = *(const bf16x8*)(QKV2 + ((size_t)(b * P1 + rq)) * NS +
                                           h * D3 + d0);
        #pragma unroll
        for (int m2 = 0; m2 < 8; ++m2) Qs[qr][d0 + m2] = (float)v8[m2];
      } else {
        #pragma unroll
        for (int m2 = 0; m2 < 8; ++m2) Qs[qr][d0 + m2] = 0.f;
      }
    }
    __syncthreads();
    const int grp = tid >> 3, k = tid & 7;
    float dot = 0.f;
    for (int d = 0; d < D3; d += 4) {
      const float4 a4 = *(const float4*)&Qs[grp][d];
      const float4 b4 = *(const float4*)&Ks[k][d];
      dot = fmaf(a4.x, b4.x, dot); dot = fmaf(a4.y, b4.y, dot);
      dot = fmaf(a4.z, b4.z, dot); dot = fmaf(a4.w, b4.w, dot);
    }
    dot *= RSCALE;
    float m = dot;
    #pragma unroll
    for (int o = 1; o < 8; o <<= 1) m = fmaxf(m, __shfl_xor(m, o, 64));
    const float e = expf(dot - m);
    float s = e;
    #pragma unroll
    for (int o = 1; o < 8; o <<= 1) s += __shfl_xor(s, o, 64);
    Pp[grp][k] = e / s;
    __syncthreads();
    if (tid < D3) {
      #pragma unroll 4
      for (int g2 = 0; g2 < 32; ++g2) {
        const int rq2 = c * 32 + g2;
        if (rq2 < P1) {
          const float mult = (rq2 == xi) ? 2.f : 1.f;
          float o = 0.f;
          #pragma unroll
          for (int kk = 0; kk < 8; ++kk) o = fmaf(Pp[g2][kk], Vs[kk][tid], o);
          acc = fmaf(mult, o, acc);
        }
      }
    }
  }
  if (tid < D3)
    FULL9b[((size_t)b * 9 + 1 + xi) * NCOL + h * D3 + tid] = (bf16_t)acc;
}

// ---------------- broadcast OUT9 -> full output ----------------
__global__ __launch_bounds__(256) void bcast_kernel(
    const float* __restrict__ OUT9, float* __restrict__ out) {
  const int idx = blockIdx.x * 256 + threadIdx.x;  // over float4s
  const int total = B_ * SEQ * (DIMX / 4);
  if (idx >= total) return;
  const int d4 = idx % (DIMX / 4);
  const int bs = idx / (DIMX / 4);
  const int s = bs % SEQ;
  const int b = bs / SEQ;
  const int row = (s == 0) ? 0 : 1 + ((s - 1) & 7);
  ((float4*)out)[idx] = ((const float4*)OUT9)[(size_t)(b * 9 + row) * (DIMX / 4) + d4];
}

// ---------------- launch ----------------
extern "C" void kernel_launch(void* const* d_in, const int* in_sizes, int n_in,
                              void* d_out, int out_size, void* d_ws, size_t ws_size,
                              hipStream_t stream) {
  const float* x  = (const float*)d_in[0];
  const float* Wq = (const float*)d_in[1];
  const float* bq = (const float*)d_in[2];
  const float* Wk = (const float*)d_in[3];
  const float* bk = (const float*)d_in[4];
  const float* Wv = (const float*)d_in[5];
  const float* bv = (const float*)d_in[6];
  const float* Wt = (const float*)d_in[7];
  const float* bt = (const float*)d_in[8];
  const float* Wf = (const float*)d_in[9];
  const float* bf = (const float*)d_in[10];
  float* out = (float*)d_out;
  (void)in_sizes; (void)n_in; (void)out_size;

  char* ws = (char*)d_ws;
  size_t off = 0;
  auto alloc_f32 = [&](size_t elems) {
    size_t a = (off + 63) & ~(size_t)63;
    off = a + elems * sizeof(float);
    return (float*)(ws + a);
  };
  auto alloc_bf16 = [&](size_t elems) {
    size_t a = (off + 63) & ~(size_t)63;
    off = a + elems * sizeof(bf16_t);
    return (bf16_t*)(ws + a);
  };

  bf16_t* T1Ub   = alloc_bf16((size_t)B_ * P1 * NCOL);
  bf16_t* TIUb   = alloc_bf16((size_t)B_ * P1 * DIMX);
  bf16_t* QKV2b  = alloc_bf16((size_t)B_ * P1 * NS);
  bf16_t* FULL9b = alloc_bf16((size_t)B_ * 9 * NCOL);
  float*  OUT9   = alloc_f32((size_t)B_ * 9 * DIMX);
  float*  Smat   = alloc_f32((size_t)B_ * H_ * P1 * P1);
  float*  CLSP   = alloc_f32((size_t)B_ * H_ * NCHUNK * CLS_STRIDE);
  float*  QKVbias= alloc_f32(NS);
  bf16_t* WqkvT  = alloc_bf16((size_t)3 * NCOL * DIMX);  // [WqT; WkT; WvT]
  bf16_t* WtT    = alloc_bf16((size_t)DIMX * NCOL);
  bf16_t* WfT    = alloc_bf16((size_t)DIMX * NCOL);

  // chunked stage-1 buffers
  const size_t remain = (ws_size > off) ? (ws_size - off) : 0;
  int Bc = 8;
  while (Bc > 1 &&
         (size_t)Bc * SEQ * (NS + DIMX) * sizeof(bf16_t) + 512 > remain)
    Bc >>= 1;
  bf16_t* XQKVb = alloc_bf16((size_t)Bc * SEQ * NS);
  bf16_t* xb    = alloc_bf16((size_t)Bc * SEQ * DIMX);

  // ---- weight transposes (one batched launch) + fused bias
  transpose_all<<<dim3(1728 * 5), 256, 0, stream>>>(
      Wq, Wk, Wv, Wt, Wf, WqkvT, WtT, WfT);
  concat_bias_kernel<<<dim3((NS + 255) / 256), 256, 0, stream>>>(bq, bk, bv, QKVbias);

  // ---- stage 1 (chunked): cast x, fused QKV GEMM (XCD-banded), attn
  for (int b0 = 0; b0 < B_; b0 += Bc) {
    const int Mrows = Bc * SEQ;
    const int n4 = Mrows * DIMX / 4;
    cast_f32_bf16<<<dim3((n4 + 255) / 256), 256, 0, stream>>>(
        x + (size_t)b0 * SEQ * DIMX, xb, n4);
    const int MT = (Mrows + 127) / 128, NT = NS / 128;
    const int XCDB = (MT + 7) / 8;
    gemm_mfma_bt<<<dim3(8 * XCDB * NT), 256, 0, stream>>>(
        xb, WqkvT, QKVbias, XQKVb, Mrows, NS, DIMX, MT, NT, 0, XCDB, 1);
    cls_part_kernel<<<dim3(Bc * H_, NCHUNK), 256, 0, stream>>>(XQKVb, CLSP, b0);
    temporal_kernel<<<dim3(Bc * H_ * PG4), 256, 0, stream>>>(XQKVb, T1Ub, b0);
  }
  cls_combine_kernel<<<dim3(B_ * H_), 256, 0, stream>>>(CLSP, FULL9b);

  // ---- ti = merge(t1u) @ Wt + bt  (bf16 out)
  {
    const int MT = (B_ * P1 + 127) / 128, NT = DIMX / 128;
    gemm_mfma_bt<<<dim3(MT * NT), 256, 0, stream>>>(
        T1Ub, WtT, bt, TIUb, B_ * P1, DIMX, NCOL, MT, NT, 4, 0, 1);
  }
  // ---- fused stage-2 QKV: [q2 | v2(Wk) | k2(Wv)] = ti @ Wqkv
  {
    const int MT = (B_ * P1 + 127) / 128, NT = NS / 128;
    gemm_mfma_bt<<<dim3(MT * NT), 256, 0, stream>>>(
        TIUb, WqkvT, QKVbias, QKV2b, B_ * P1, NS, DIMX, MT, NT, 4, 0, 1);
  }

  // ---- stage-2 attentions -> FULL9 rows 1..8
  xi0_scores_mfma<<<dim3(2, 2, B_ * H_), 256, 0, stream>>>(QKV2b, Smat);
  xi0_finish_kernel<<<dim3(B_ * H_), 256, 0, stream>>>(Smat, QKV2b, FULL9b);
  stage2_xi_kernel<<<dim3(B_ * H_ * 7), 256, 0, stream>>>(QKV2b, FULL9b);

  // ---- final projection on the 9 unique rows per batch
  {
    const int MT = 1, NT = DIMX / 128;
    gemm_mfma_bt<<<dim3(MT * NT), 256, 0, stream>>>(
        FULL9b, WfT, bf, OUT9, B_ * 9, DIMX, NCOL, MT, NT, 1, 0, 0);
  }

  // ---- broadcast to the full (B, 1569, 768) output
  {
    const int total4 = B_ * SEQ * (DIMX / 4);
    bcast_kernel<<<dim3((total4 + 255) / 256), 256, 0, stream>>>(OUT9, out);
  }
}

// Round 8
// 816.420 us; speedup vs baseline: 1.0391x; 1.0391x over previous
//
#include <hip/hip_runtime.h>
#include <math.h>

// Problem constants
#define B_    8
#define SEQ   1569      // 1 + 196*8
#define DIMX  768
#define H_    12
#define D3    192       // head dim slice (3*DH)
#define F_    8
#define NP    196
#define P1    195       // patches kept per frame
#define NCOL  2304      // 3*DIM
#define NS    6912      // fused QKV row stride (3*NCOL)
#define RSCALE (1.0f/96.0f)
#define NCHUNK 16       // cls split-K chunks
#define CH     99       // keys per chunk (16*99 >= 1569)
#define CLS_STRIDE 196  // 192 o + m + l (+pad)
#define PG4   49        // ceil(P1/4) patch groups for temporal

typedef __bf16 bf16_t;
typedef bf16_t bf16x8 __attribute__((ext_vector_type(8)));
typedef float  f32x4  __attribute__((ext_vector_type(4)));

// async global->LDS, 16B per lane; LDS dest = wave-uniform base + lane*16
__device__ __forceinline__ void load_lds16(const bf16_t* g, bf16_t* l) {
  __builtin_amdgcn_global_load_lds(
      (const __attribute__((address_space(1))) void*)g,
      (__attribute__((address_space(3))) void*)l, 16, 0, 0);
}

// ---------------- block reduction helpers (blockDim == 256) ----------------
__device__ __forceinline__ float block_max256(float v, float* red) {
  #pragma unroll
  for (int o = 32; o > 0; o >>= 1) v = fmaxf(v, __shfl_xor(v, o, 64));
  __syncthreads();
  if ((threadIdx.x & 63) == 0) red[threadIdx.x >> 6] = v;
  __syncthreads();
  return fmaxf(fmaxf(red[0], red[1]), fmaxf(red[2], red[3]));
}

__device__ __forceinline__ float block_sum256(float v, float* red) {
  #pragma unroll
  for (int o = 32; o > 0; o >>= 1) v += __shfl_xor(v, o, 64);
  __syncthreads();
  if ((threadIdx.x & 63) == 0) red[threadIdx.x >> 6] = v;
  __syncthreads();
  return red[0] + red[1] + red[2] + red[3];
}

// ---------------- cast fp32 -> bf16 (vector of 4) ----------------
__global__ __launch_bounds__(256) void cast_f32_bf16(
    const float* __restrict__ in, bf16_t* __restrict__ out, int n4) {
  const int i = blockIdx.x * 256 + threadIdx.x;
  if (i >= n4) return;
  const float4 v = ((const float4*)in)[i];
  bf16_t o4[4] = {(bf16_t)v.x, (bf16_t)v.y, (bf16_t)v.z, (bf16_t)v.w};
  ((uint2*)out)[i] = *(uint2*)o4;
}

// ---------------- concat q/k/v biases ----------------
__global__ __launch_bounds__(256) void concat_bias_kernel(
    const float* __restrict__ bq, const float* __restrict__ bk,
    const float* __restrict__ bv, float* __restrict__ qkvb) {
  const int i = blockIdx.x * 256 + threadIdx.x;
  if (i >= NS) return;
  float v;
  if (i < NCOL) v = bq[i];
  else if (i < 2 * NCOL) v = bk[i - NCOL];
  else v = bv[i - 2 * NCOL];
  qkvb[i] = v;
}

// ---------------- batched transpose+cast of the 5 weight matrices ----------
// grid = 1728 * 5; mats 0-2: 768x2304 -> WqkvT rows; mats 3-4: 2304x768.
__global__ __launch_bounds__(256) void transpose_all(
    const float* __restrict__ Wq, const float* __restrict__ Wk,
    const float* __restrict__ Wv, const float* __restrict__ Wt,
    const float* __restrict__ Wf, bf16_t* __restrict__ WqkvT,
    bf16_t* __restrict__ WtT, bf16_t* __restrict__ WfT) {
  __shared__ float t[32][33];
  const int bid = blockIdx.x;
  const int mat = bid / 1728, tt = bid % 1728;
  const float* W; bf16_t* WT; int Kd, Nd, nt, kt;
  if (mat < 3) {
    Kd = DIMX; Nd = NCOL;
    W = (mat == 0) ? Wq : ((mat == 1) ? Wk : Wv);
    WT = WqkvT + (size_t)mat * NCOL * DIMX;
    nt = tt % 72; kt = tt / 72;
  } else {
    Kd = NCOL; Nd = DIMX;
    W = (mat == 3) ? Wt : Wf;
    WT = (mat == 3) ? WtT : WfT;
    nt = tt % 24; kt = tt / 24;
  }
  const int bn = nt * 32, bk = kt * 32;
  const int tx = threadIdx.x & 31, ty = threadIdx.x >> 5;  // 32 x 8
  #pragma unroll
  for (int i = 0; i < 32; i += 8)
    t[ty + i][tx] = W[(size_t)(bk + ty + i) * Nd + bn + tx];
  __syncthreads();
  #pragma unroll
  for (int i = 0; i < 32; i += 8)
    WT[(size_t)(bn + ty + i) * Kd + bk + tx] = (bf16_t)t[tx][ty + i];
}

// ---------------- bf16 MFMA GEMM: C = A @ BT^T + bias ----------------
// Single-buffered, BK=64: 8 global_load_lds + 32 MFMAs per K-iteration
// (half the latency exposures of BK=32). Fragment-major LDS: each 16-row x
// 64-col block is 8 segs x 16 rows of 16B cells; both the staging scatter
// (dest = base + lane*16) and the fragment read (base + half*1024B + lane*16)
// are linear in lane -> zero bank conflicts. K%64==0, N%128==0.
// XCDB>0: XCD x owns contiguous m-tile band (A band L2-resident per XCD).
__global__ __launch_bounds__(256) void gemm_mfma_bt(
    const bf16_t* __restrict__ A, const bf16_t* __restrict__ BT,
    const float* __restrict__ bias, void* __restrict__ C,
    int M, int N, int K, int MT, int NT, int GROUPM, int XCDB, int outBf16) {
  __shared__ bf16_t As[128 * 64];
  __shared__ bf16_t Bs[128 * 64];
  const int tid  = threadIdx.x;
  const int wave = tid >> 6, lane = tid & 63;

  int m_tile, n_tile;
  const int pid = blockIdx.x;
  if (XCDB > 0) {
    const int xcd = pid & 7, q = pid >> 3;
    m_tile = xcd * XCDB + q % XCDB;
    n_tile = q / XCDB;
    if (m_tile >= MT) return;
  } else {
    const int npg   = GROUPM * NT;
    const int group = pid / npg;
    const int first_m = group * GROUPM;
    int gsm = MT - first_m; if (gsm > GROUPM) gsm = GROUPM;
    const int lpid  = pid % npg;
    m_tile = first_m + lpid % gsm;
    n_tile = lpid / gsm;
  }
  const int row0 = m_tile * 128, col0 = n_tile * 128;

  // staging: lane (fr, kg) fetches row fr, k-seg kg (8 cols) of a 16-row block
  const int fr = lane & 15, kg = lane >> 4;
  int ra0 = row0 + wave * 32 + fr;
  int ra1 = ra0 + 16;
  if (ra0 >= M) ra0 = M - 1;
  if (ra1 >= M) ra1 = M - 1;
  const bf16_t* Ap0 = A + (size_t)ra0 * K + kg * 8;
  const bf16_t* Ap1 = A + (size_t)ra1 * K + kg * 8;
  const bf16_t* Bp0 = BT + (size_t)(col0 + wave * 32 + fr) * K + kg * 8;
  const bf16_t* Bp1 = Bp0 + (size_t)16 * K;
  const int la0 = (wave * 2 + 0) * 1024, la1 = (wave * 2 + 1) * 1024;

  const int mb = (wave & 1) * 4,  nb = (wave >> 1) * 4;   // 16-row block idx
  const int m0 = (wave & 1) * 64, n0 = (wave >> 1) * 64;
  f32x4 acc[4][4] = {};

  for (int k0 = 0; k0 < K; k0 += 64) {
    load_lds16(Ap0 + k0,      &As[la0]);
    load_lds16(Ap0 + k0 + 32, &As[la0 + 512]);
    load_lds16(Ap1 + k0,      &As[la1]);
    load_lds16(Ap1 + k0 + 32, &As[la1 + 512]);
    load_lds16(Bp0 + k0,      &Bs[la0]);
    load_lds16(Bp0 + k0 + 32, &Bs[la0 + 512]);
    load_lds16(Bp1 + k0,      &Bs[la1]);
    load_lds16(Bp1 + k0 + 32, &Bs[la1 + 512]);
    __syncthreads();

    #pragma unroll
    for (int h = 0; h < 2; ++h) {
      bf16x8 af[4], bfr[4];
      #pragma unroll
      for (int i = 0; i < 4; ++i) {
        af[i]  = *(const bf16x8*)&As[(mb + i) * 1024 + h * 512 + lane * 8];
        bfr[i] = *(const bf16x8*)&Bs[(nb + i) * 1024 + h * 512 + lane * 8];
      }
      #pragma unroll
      for (int i = 0; i < 4; ++i)
        #pragma unroll
        for (int j = 0; j < 4; ++j)
          acc[i][j] = __builtin_amdgcn_mfma_f32_16x16x32_bf16(
              af[i], bfr[j], acc[i][j], 0, 0, 0);
    }
    __syncthreads();
  }

  const int cc = lane & 15, cr4 = (lane >> 4) * 4;
  #pragma unroll
  for (int i = 0; i < 4; ++i) {
    #pragma unroll
    for (int j = 0; j < 4; ++j) {
      const int col = col0 + n0 + j * 16 + cc;
      const float bcol = bias[col];
      #pragma unroll
      for (int reg = 0; reg < 4; ++reg) {
        const int r = row0 + m0 + i * 16 + cr4 + reg;
        if (r < M) {
          const float v = acc[i][j][reg] + bcol;
          if (outBf16) ((bf16_t*)C)[(size_t)r * N + col] = (bf16_t)v;
          else         ((float*)C)[(size_t)r * N + col] = v;
        }
      }
    }
  }
}

// ---------------- xi0 scores via MFMA: S = RSCALE * Q2 @ K2^T per (b,h) ------
// grid (2, 2, 96). Q at QKV2 col 0, K at col 2*NCOL; row stride NS.
__global__ __launch_bounds__(256) void xi0_scores_mfma(
    const bf16_t* __restrict__ QKV2, float* __restrict__ Smat) {
  __shared__ bf16_t As[128 * 32];
  __shared__ bf16_t Bs[128 * 32];
  const int tid  = threadIdx.x;
  const int wave = tid >> 6, lane = tid & 63;
  const int row0 = blockIdx.x * 128, col0 = blockIdx.y * 128;
  const int bh = blockIdx.z;
  const int b = bh / H_, h = bh % H_;
  const bf16_t* Abase = QKV2 + (size_t)b * P1 * NS + h * D3;             // Q2
  const bf16_t* Bbase = QKV2 + (size_t)b * P1 * NS + 2 * NCOL + h * D3;  // K2

  const int fr = lane & 15, kg = lane >> 4;
  int ra0 = row0 + wave * 32 + fr;
  int ra1 = ra0 + 16;
  if (ra0 >= P1) ra0 = P1 - 1;
  if (ra1 >= P1) ra1 = P1 - 1;
  int cb0 = col0 + wave * 32 + fr;
  int cb1 = cb0 + 16;
  if (cb0 >= P1) cb0 = P1 - 1;
  if (cb1 >= P1) cb1 = P1 - 1;
  const bf16_t* Ap0 = Abase + (size_t)ra0 * NS + kg * 8;
  const bf16_t* Ap1 = Abase + (size_t)ra1 * NS + kg * 8;
  const bf16_t* Bp0 = Bbase + (size_t)cb0 * NS + kg * 8;
  const bf16_t* Bp1 = Bbase + (size_t)cb1 * NS + kg * 8;
  bf16_t* lA0 = &As[(wave * 2 + 0) * 512];
  bf16_t* lA1 = &As[(wave * 2 + 1) * 512];
  bf16_t* lB0 = &Bs[(wave * 2 + 0) * 512];
  bf16_t* lB1 = &Bs[(wave * 2 + 1) * 512];

  const int m0 = (wave & 1) * 64, n0 = (wave >> 1) * 64;
  const int mb = (wave & 1) * 4,  nb = (wave >> 1) * 4;
  f32x4 acc[4][4] = {};

  for (int k0 = 0; k0 < D3; k0 += 32) {
    load_lds16(Ap0 + k0, lA0);
    load_lds16(Ap1 + k0, lA1);
    load_lds16(Bp0 + k0, lB0);
    load_lds16(Bp1 + k0, lB1);
    __syncthreads();
    bf16x8 af[4], bfr[4];
    #pragma unroll
    for (int i = 0; i < 4; ++i) {
      af[i]  = *(const bf16x8*)&As[(mb + i) * 512 + lane * 8];
      bfr[i] = *(const bf16x8*)&Bs[(nb + i) * 512 + lane * 8];
    }
    #pragma unroll
    for (int i = 0; i < 4; ++i)
      #pragma unroll
      for (int j = 0; j < 4; ++j)
        acc[i][j] = __builtin_amdgcn_mfma_f32_16x16x32_bf16(
            af[i], bfr[j], acc[i][j], 0, 0, 0);
    __syncthreads();
  }

  float* S = Smat + (size_t)bh * P1 * P1;
  const int cc = lane & 15, cr4 = (lane >> 4) * 4;
  #pragma unroll
  for (int i = 0; i < 4; ++i)
    #pragma unroll
    for (int j = 0; j < 4; ++j) {
      const int col = col0 + n0 + j * 16 + cc;
      #pragma unroll
      for (int reg = 0; reg < 4; ++reg) {
        const int r = row0 + m0 + i * 16 + cr4 + reg;
        if (r < P1 && col < P1) S[(size_t)r * P1 + col] = acc[i][j][reg] * RSCALE;
      }
    }
}

// ---------------- xi0 finish: wave-per-row stats, colsum, PV ----------------
__global__ __launch_bounds__(256) void xi0_finish_kernel(
    const float* __restrict__ Smat, const bf16_t* __restrict__ QKV2,
    bf16_t* __restrict__ FULL9b) {
  const int bh = blockIdx.x;
  const int b = bh / H_, h = bh % H_;
  __shared__ float mrow[P1], inv_l[P1], g[P1];
  const float* S = Smat + (size_t)bh * P1 * P1;
  const int tid = threadIdx.x;
  const int wave = tid >> 6, lane = tid & 63;

  // row stats: one wave per row, coalesced 64-wide scans + shuffle reduce
  for (int r = wave; r < P1; r += 4) {
    const float* Sr = S + (size_t)r * P1;
    const float s0 = Sr[lane];
    const float s1 = Sr[64 + lane];
    const float s2 = Sr[128 + lane];
    const float s3 = (lane < 3) ? Sr[192 + lane] : -1e30f;
    float m = fmaxf(fmaxf(s0, s1), fmaxf(s2, s3));
    #pragma unroll
    for (int o = 1; o < 64; o <<= 1) m = fmaxf(m, __shfl_xor(m, o, 64));
    float e = expf(s0 - m) * ((lane == 0) ? 2.f : 1.f) + expf(s1 - m) +
              expf(s2 - m) + ((lane < 3) ? expf(s3 - m) : 0.f);
    #pragma unroll
    for (int o = 1; o < 64; o <<= 1) e += __shfl_xor(e, o, 64);
    if (lane == 0) {
      mrow[r] = m;
      inv_l[r] = ((r == 0) ? 2.f : 1.f) / e;   // query-row multiplicity / denom
    }
  }
  __syncthreads();
  if (tid < P1) {
    float s = 0.f;
    for (int r = 0; r < P1; ++r)
      s += expf(S[(size_t)r * P1 + tid] - mrow[r]) * inv_l[r];
    g[tid] = s * ((tid == 0) ? 2.f : 1.f);       // key-0 multiplicity
  }
  __syncthreads();
  if (tid < D3) {
    float acc = 0.f;
    const bf16_t* vbase = QKV2 + (size_t)b * P1 * NS + NCOL + h * D3 + tid;  // V2
    for (int k = 0; k < P1; ++k)
      acc = fmaf(g[k], (float)vbase[(size_t)k * NS], acc);
    FULL9b[((size_t)b * 9 + 1) * NCOL + h * D3 + tid] = (bf16_t)acc;
  }
}

// ---------------- cls attention, split over keys ----------------
// XQKV row layout: [q | k(Wk) | v(Wv)], stride NS.
__global__ __launch_bounds__(256) void cls_part_kernel(
    const bf16_t* __restrict__ XQKV, float* __restrict__ CLSP, int b0) {
  const int h  = blockIdx.x % H_;
  const int bl = blockIdx.x / H_;
  const int b  = b0 + bl;
  const int c  = blockIdx.y;
  const int t0 = c * CH;
  const int tend = (t0 + CH < SEQ) ? t0 + CH : SEQ;
  __shared__ float qs[D3];
  __shared__ float sc[CH];
  __shared__ float red[4];
  const int tid = threadIdx.x;

  const bf16_t* Qr = XQKV + (size_t)bl * SEQ * NS + h * D3;
  if (tid < 24) {
    const bf16x8 q8 = *(const bf16x8*)(Qr + tid * 8);
    #pragma unroll
    for (int m2 = 0; m2 < 8; ++m2) qs[tid * 8 + m2] = (float)q8[m2];
  }
  __syncthreads();

  float lmax = -1e30f;
  for (int t = t0 + tid; t < tend; t += 256) {
    const bf16_t* kr = XQKV + ((size_t)bl * SEQ + t) * NS + NCOL + h * D3;
    float acc = 0.f;
    #pragma unroll 3
    for (int d = 0; d < D3; d += 8) {
      const bf16x8 k8 = *(const bf16x8*)(kr + d);
      #pragma unroll
      for (int m2 = 0; m2 < 8; ++m2) acc = fmaf(qs[d + m2], (float)k8[m2], acc);
    }
    acc *= RSCALE;
    sc[t - t0] = acc;
    lmax = fmaxf(lmax, acc);
  }
  const float m = block_max256(lmax, red);
  float lsum = 0.f;
  for (int t = t0 + tid; t < tend; t += 256) {
    const float e = expf(sc[t - t0] - m);
    sc[t - t0] = e;
    lsum += e;
  }
  const float L = block_sum256(lsum, red);
  __syncthreads();

  float* P = CLSP + ((size_t)(b * H_ + h) * NCHUNK + c) * CLS_STRIDE;
  if (tid < D3) {
    float acc = 0.f;
    const bf16_t* vbase = XQKV + ((size_t)bl * SEQ + t0) * NS + 2 * NCOL + h * D3 + tid;
    for (int t = t0; t < tend; ++t)
      acc = fmaf(sc[t - t0], (float)vbase[(size_t)(t - t0) * NS], acc);
    P[tid] = acc;
  }
  if (tid == 192) P[192] = m;
  if (tid == 193) P[193] = L;
}

// ---------------- cls combine: merge NCHUNK partials ----------------
__global__ __launch_bounds__(256) void cls_combine_kernel(
    const float* __restrict__ CLSP, bf16_t* __restrict__ FULL9b) {
  const int bh = blockIdx.x;
  const int tid = threadIdx.x;
  const float* P = CLSP + (size_t)bh * NCHUNK * CLS_STRIDE;

  float M = -1e30f;
  #pragma unroll
  for (int c = 0; c < NCHUNK; ++c) M = fmaxf(M, P[c * CLS_STRIDE + 192]);
  float L = 0.f;
  float w[NCHUNK];
  #pragma unroll
  for (int c = 0; c < NCHUNK; ++c) {
    w[c] = expf(P[c * CLS_STRIDE + 192] - M);
    L += P[c * CLS_STRIDE + 193] * w[c];
  }
  if (tid < D3) {
    float acc = 0.f;
    #pragma unroll
    for (int c = 0; c < NCHUNK; ++c)
      acc = fmaf(w[c], P[c * CLS_STRIDE + tid], acc);
    const int b = bh / H_, h = bh % H_;
    FULL9b[((size_t)b * 9 + 0) * NCOL + h * D3 + tid] = (bf16_t)(acc / L);
  }
}

// ---------------- temporal attention, 4 patches (waves) per block ----------
// q col 0, k col 2*NCOL (Wv proj!), v col NCOL (Wk proj!).
__global__ __launch_bounds__(256) void temporal_kernel(
    const bf16_t* __restrict__ XQKV, bf16_t* __restrict__ T1U, int b0) {
  const int id = blockIdx.x;
  const int pg = id % PG4;
  const int h  = (id / PG4) % H_;
  const int bl = id / (PG4 * H_);
  const int b  = b0 + bl;
  const int wave = threadIdx.x >> 6, lane = threadIdx.x & 63;
  __shared__ float qs[4][8][196], ks[4][8][196];

  int pi = pg * 4 + wave;
  const bool act = (pi < P1);
  if (!act) pi = P1 - 1;

  #pragma unroll
  for (int i = 0; i < 6; ++i) {
    const int idx = lane + 64 * i;  // 0..383: [0,192) -> qs, [192,384) -> ks
    const int arr = idx / 192;
    const int c = idx % 192;        // chunk of 8 dims
    const int f = c / 24, d0 = (c % 24) * 8;
    const size_t base = ((size_t)bl * SEQ + (size_t)f * NP + pi + 2) * NS +
                        (arr ? 2 * NCOL : 0) + h * D3 + d0;
    const bf16x8 v8 = *(const bf16x8*)(XQKV + base);
    float* dst = arr ? &ks[wave][f][d0] : &qs[wave][f][d0];
    #pragma unroll
    for (int m2 = 0; m2 < 8; ++m2) dst[m2] = (float)v8[m2];
  }
  __syncthreads();

  const int f = lane >> 3, g = lane & 7;
  float s = 0.f;
  for (int d = 0; d < D3; d += 4) {
    const float4 a4 = *(const float4*)&qs[wave][f][d];
    const float4 b4 = *(const float4*)&ks[wave][g][d];
    s = fmaf(a4.x, b4.x, s); s = fmaf(a4.y, b4.y, s);
    s = fmaf(a4.z, b4.z, s); s = fmaf(a4.w, b4.w, s);
  }
  s *= RSCALE;

  float m = s;
  #pragma unroll
  for (int o = 1; o < 8; o <<= 1) m = fmaxf(m, __shfl_xor(m, o, 64));
  const float e = expf(s - m);
  float sum = e;
  #pragma unroll
  for (int o = 1; o < 8; o <<= 1) sum += __shfl_xor(sum, o, 64);
  float a = e / sum;
  #pragma unroll
  for (int o = 8; o < 64; o <<= 1) a += __shfl_xor(a, o, 64);  // column sums
  float wg[8];
  #pragma unroll
  for (int gg = 0; gg < 8; ++gg) wg[gg] = __shfl(a, gg, 64);

  if (act) {
    const size_t vrow = (size_t)bl * SEQ * NS + NCOL + h * D3;  // values: Wk proj
    #pragma unroll
    for (int i = 0; i < 3; ++i) {
      const int d = lane + 64 * i;
      float o = 0.f;
      #pragma unroll
      for (int gg = 0; gg < 8; ++gg) {
        const bf16_t vv = XQKV[vrow + ((size_t)gg * NP + pi + 2) * NS + d];
        o = fmaf(wg[gg], (float)vv, o);
      }
      T1U[((size_t)b * P1 + pi) * NCOL + h * D3 + d] = (bf16_t)o;
    }
  }
}

// ---------------- stage-2, xi = 1..7: 195(+dup row xi) queries over 8 keys ----
// QKV2 layout: [q2 | v2(Wk) | k2(Wv)], stride NS.
__global__ __launch_bounds__(256) void stage2_xi_kernel(
    const bf16_t* __restrict__ QKV2, bf16_t* __restrict__ FULL9b) {
  const int xi = 1 + blockIdx.x % 7;
  const int h  = (blockIdx.x / 7) % H_;
  const int b  = blockIdx.x / (7 * H_);
  __shared__ float Ks[8][196], Vs[8][196], Qs[32][196];
  __shared__ float Pp[32][8];
  const int tid = threadIdx.x;

  for (int idx = tid; idx < 192; idx += 256) {          // keys: col 2*NCOL
    const int k = idx / 24, d0 = (idx % 24) * 8;
    const bf16x8 v8 = *(const bf16x8*)(QKV2 + ((size_t)(b * P1 + xi + k)) * NS +
                                       2 * NCOL + h * D3 + d0);
    #pragma unroll
    for (int m2 = 0; m2 < 8; ++m2) Ks[k][d0 + m2] = (float)v8[m2];
  }
  for (int idx = tid; idx < 192; idx += 256) {          // values: col NCOL
    const int k = idx / 24, d0 = (idx % 24) * 8;
    const bf16x8 v8 = *(const bf16x8*)(QKV2 + ((size_t)(b * P1 + xi + k)) * NS +
                                       NCOL + h * D3 + d0);
    #pragma unroll
    for (int m2 = 0; m2 < 8; ++m2) Vs[k][d0 + m2] = (float)v8[m2];
  }

  float acc = 0.f;  // for d = tid (tid < 192)
  for (int c = 0; c < 7; ++c) {
    __syncthreads();
    for (int idx = tid; idx < 768; idx += 256) {        // 32 queries x 192 dims
      const int qr = idx / 24, d0 = (idx % 24) * 8;
      const int rq = c * 32 + qr;
      if (rq < P1) {
        const bf16x8 v8 = *(const bf16x8*)(QKV2 + ((size_t)(b * P1 + rq)) * NS +
                                           h * D3 + d0);
        #pragma unroll
        for (int m2 = 0; m2 < 8; ++m2) Qs[qr][d0 + m2] = (float)v8[m2];
      } else {
        #pragma unroll
        for (int m2 = 0; m2 < 8; ++m2) Qs[qr][d0 + m2] = 0.f;
      }
    }
    __syncthreads();
    const int grp = tid >> 3, k = tid & 7;
    float dot = 0.f;
    for (int d = 0; d < D3; d += 4) {
      const float4 a4 = *(const float4*)&Qs[grp][d];
      const float4 b4 = *(const float4*)&Ks[k][d];
      dot = fmaf(a4.x, b4.x, dot); dot = fmaf(a4.y, b4.y, dot);
      dot = fmaf(a4.z, b4.z, dot); dot = fmaf(a4.w, b4.w, dot);
    }
    dot *= RSCALE;
    float m = dot;
    #pragma unroll
    for (int o = 1; o < 8; o <<= 1) m = fmaxf(m, __shfl_xor(m, o, 64));
    const float e = expf(dot - m);
    float s = e;
    #pragma unroll
    for (int o = 1; o < 8; o <<= 1) s += __shfl_xor(s, o, 64);
    Pp[grp][k] = e / s;
    __syncthreads();
    if (tid < D3) {
      #pragma unroll 4
      for (int g2 = 0; g2 < 32; ++g2) {
        const int rq2 = c * 32 + g2;
        if (rq2 < P1) {
          const float mult = (rq2 == xi) ? 2.f : 1.f;
          float o = 0.f;
          #pragma unroll
          for (int kk = 0; kk < 8; ++kk) o = fmaf(Pp[g2][kk], Vs[kk][tid], o);
          acc = fmaf(mult, o, acc);
        }
      }
    }
  }
  if (tid < D3)
    FULL9b[((size_t)b * 9 + 1 + xi) * NCOL + h * D3 + tid] = (bf16_t)acc;
}

// ---------------- broadcast OUT9 -> full output ----------------
__global__ __launch_bounds__(256) void bcast_kernel(
    const float* __restrict__ OUT9, float* __restrict__ out) {
  const int idx = blockIdx.x * 256 + threadIdx.x;  // over float4s
  const int total = B_ * SEQ * (DIMX / 4);
  if (idx >= total) return;
  const int d4 = idx % (DIMX / 4);
  const int bs = idx / (DIMX / 4);
  const int s = bs % SEQ;
  const int b = bs / SEQ;
  const int row = (s == 0) ? 0 : 1 + ((s - 1) & 7);
  ((float4*)out)[idx] = ((const float4*)OUT9)[(size_t)(b * 9 + row) * (DIMX / 4) + d4];
}

// ---------------- launch ----------------
extern "C" void kernel_launch(void* const* d_in, const int* in_sizes, int n_in,
                              void* d_out, int out_size, void* d_ws, size_t ws_size,
                              hipStream_t stream) {
  const float* x  = (const float*)d_in[0];
  const float* Wq = (const float*)d_in[1];
  const float* bq = (const float*)d_in[2];
  const float* Wk = (const float*)d_in[3];
  const float* bk = (const float*)d_in[4];
  const float* Wv = (const float*)d_in[5];
  const float* bv = (const float*)d_in[6];
  const float* Wt = (const float*)d_in[7];
  const float* bt = (const float*)d_in[8];
  const float* Wf = (const float*)d_in[9];
  const float* bf = (const float*)d_in[10];
  float* out = (float*)d_out;
  (void)in_sizes; (void)n_in; (void)out_size;

  char* ws = (char*)d_ws;
  size_t off = 0;
  auto alloc_f32 = [&](size_t elems) {
    size_t a = (off + 63) & ~(size_t)63;
    off = a + elems * sizeof(float);
    return (float*)(ws + a);
  };
  auto alloc_bf16 = [&](size_t elems) {
    size_t a = (off + 63) & ~(size_t)63;
    off = a + elems * sizeof(bf16_t);
    return (bf16_t*)(ws + a);
  };

  bf16_t* T1Ub   = alloc_bf16((size_t)B_ * P1 * NCOL);
  bf16_t* TIUb   = alloc_bf16((size_t)B_ * P1 * DIMX);
  bf16_t* QKV2b  = alloc_bf16((size_t)B_ * P1 * NS);
  bf16_t* FULL9b = alloc_bf16((size_t)B_ * 9 * NCOL);
  float*  OUT9   = alloc_f32((size_t)B_ * 9 * DIMX);
  float*  Smat   = alloc_f32((size_t)B_ * H_ * P1 * P1);
  float*  CLSP   = alloc_f32((size_t)B_ * H_ * NCHUNK * CLS_STRIDE);
  float*  QKVbias= alloc_f32(NS);
  bf16_t* WqkvT  = alloc_bf16((size_t)3 * NCOL * DIMX);  // [WqT; WkT; WvT]
  bf16_t* WtT    = alloc_bf16((size_t)DIMX * NCOL);
  bf16_t* WfT    = alloc_bf16((size_t)DIMX * NCOL);

  // chunked stage-1 buffers
  const size_t remain = (ws_size > off) ? (ws_size - off) : 0;
  int Bc = 8;
  while (Bc > 1 &&
         (size_t)Bc * SEQ * (NS + DIMX) * sizeof(bf16_t) + 512 > remain)
    Bc >>= 1;
  bf16_t* XQKVb = alloc_bf16((size_t)Bc * SEQ * NS);
  bf16_t* xb    = alloc_bf16((size_t)Bc * SEQ * DIMX);

  // ---- weight transposes (one batched launch) + fused bias
  transpose_all<<<dim3(1728 * 5), 256, 0, stream>>>(
      Wq, Wk, Wv, Wt, Wf, WqkvT, WtT, WfT);
  concat_bias_kernel<<<dim3((NS + 255) / 256), 256, 0, stream>>>(bq, bk, bv, QKVbias);

  // ---- stage 1 (chunked): cast x, fused QKV GEMM (XCD-banded), attn
  for (int b0 = 0; b0 < B_; b0 += Bc) {
    const int Mrows = Bc * SEQ;
    const int n4 = Mrows * DIMX / 4;
    cast_f32_bf16<<<dim3((n4 + 255) / 256), 256, 0, stream>>>(
        x + (size_t)b0 * SEQ * DIMX, xb, n4);
    const int MT = (Mrows + 127) / 128, NT = NS / 128;
    const int XCDB = (MT + 7) / 8;
    gemm_mfma_bt<<<dim3(8 * XCDB * NT), 256, 0, stream>>>(
        xb, WqkvT, QKVbias, XQKVb, Mrows, NS, DIMX, MT, NT, 0, XCDB, 1);
    cls_part_kernel<<<dim3(Bc * H_, NCHUNK), 256, 0, stream>>>(XQKVb, CLSP, b0);
    temporal_kernel<<<dim3(Bc * H_ * PG4), 256, 0, stream>>>(XQKVb, T1Ub, b0);
  }
  cls_combine_kernel<<<dim3(B_ * H_), 256, 0, stream>>>(CLSP, FULL9b);

  // ---- ti = merge(t1u) @ Wt + bt  (bf16 out)
  {
    const int MT = (B_ * P1 + 127) / 128, NT = DIMX / 128;
    gemm_mfma_bt<<<dim3(MT * NT), 256, 0, stream>>>(
        T1Ub, WtT, bt, TIUb, B_ * P1, DIMX, NCOL, MT, NT, 4, 0, 1);
  }
  // ---- fused stage-2 QKV: [q2 | v2(Wk) | k2(Wv)] = ti @ Wqkv
  {
    const int MT = (B_ * P1 + 127) / 128, NT = NS / 128;
    gemm_mfma_bt<<<dim3(MT * NT), 256, 0, stream>>>(
        TIUb, WqkvT, QKVbias, QKV2b, B_ * P1, NS, DIMX, MT, NT, 4, 0, 1);
  }

  // ---- stage-2 attentions -> FULL9 rows 1..8
  xi0_scores_mfma<<<dim3(2, 2, B_ * H_), 256, 0, stream>>>(QKV2b, Smat);
  xi0_finish_kernel<<<dim3(B_ * H_), 256, 0, stream>>>(Smat, QKV2b, FULL9b);
  stage2_xi_kernel<<<dim3(B_ * H_ * 7), 256, 0, stream>>>(QKV2b, FULL9b);

  // ---- final projection on the 9 unique rows per batch
  {
    const int MT = 1, NT = DIMX / 128;
    gemm_mfma_bt<<<dim3(MT * NT), 256, 0, stream>>>(
        FULL9b, WfT, bf, OUT9, B_ * 9, DIMX, NCOL, MT, NT, 1, 0, 0);
  }

  // ---- broadcast to the full (B, 1569, 768) output
  {
    const int total4 = B_ * SEQ * (DIMX / 4);
    bcast_kernel<<<dim3((total4 + 255) / 256), 256, 0, stream>>>(OUT9, out);
  }
}

// Round 9
// 669.184 us; speedup vs baseline: 1.2677x; 1.2200x over previous
//
#include <hip/hip_runtime.h>
#include <math.h>

// Problem constants
#define B_    8
#define SEQ   1569      // 1 + 196*8
#define DIMX  768
#define H_    12
#define D3    192       // head dim slice (3*DH)
#define F_    8
#define NP    196
#define P1    195       // patches kept per frame
#define NCOL  2304      // 3*DIM
#define NS    6912      // fused QKV row stride (3*NCOL)
#define RSCALE (1.0f/96.0f)
#define NCHUNK 16       // cls split-K chunks
#define CH     99       // keys per chunk (16*99 >= 1569)
#define CLS_STRIDE 196  // 192 o + m + l (+pad)
#define PG4   49        // ceil(P1/4) patch groups for temporal

typedef __bf16 bf16_t;
typedef bf16_t bf16x8 __attribute__((ext_vector_type(8)));
typedef float  f32x4  __attribute__((ext_vector_type(4)));

// async global->LDS, 16B per lane; LDS dest = wave-uniform base + lane*16
__device__ __forceinline__ void load_lds16(const bf16_t* g, bf16_t* l) {
  __builtin_amdgcn_global_load_lds(
      (const __attribute__((address_space(1))) void*)g,
      (__attribute__((address_space(3))) void*)l, 16, 0, 0);
}

// ---------------- block reduction helpers (blockDim == 256) ----------------
__device__ __forceinline__ float block_max256(float v, float* red) {
  #pragma unroll
  for (int o = 32; o > 0; o >>= 1) v = fmaxf(v, __shfl_xor(v, o, 64));
  __syncthreads();
  if ((threadIdx.x & 63) == 0) red[threadIdx.x >> 6] = v;
  __syncthreads();
  return fmaxf(fmaxf(red[0], red[1]), fmaxf(red[2], red[3]));
}

__device__ __forceinline__ float block_sum256(float v, float* red) {
  #pragma unroll
  for (int o = 32; o > 0; o >>= 1) v += __shfl_xor(v, o, 64);
  __syncthreads();
  if ((threadIdx.x & 63) == 0) red[threadIdx.x >> 6] = v;
  __syncthreads();
  return red[0] + red[1] + red[2] + red[3];
}

// ---------------- concat q/k/v biases ----------------
__global__ __launch_bounds__(256) void concat_bias_kernel(
    const float* __restrict__ bq, const float* __restrict__ bk,
    const float* __restrict__ bv, float* __restrict__ qkvb) {
  const int i = blockIdx.x * 256 + threadIdx.x;
  if (i >= NS) return;
  float v;
  if (i < NCOL) v = bq[i];
  else if (i < 2 * NCOL) v = bk[i - NCOL];
  else v = bv[i - 2 * NCOL];
  qkvb[i] = v;
}

// ---------------- cast fp32 -> bf16 with panel swizzle ----------------
// Output layout: panels of 16 rows x 32 k-cols, lane-linear: panel p =
// ms*KP + kp (KP = K/32); within panel, lane L=(fr=L&15, kg=L>>4) holds
// row ms*16+fr, cols kp*32+kg*8..+8 at offset p*512 + L*8.
// Rows >= Mreal are clamped (content masked later at the GEMM C-store).
__global__ __launch_bounds__(256) void cast_swizzle(
    const float* __restrict__ x, bf16_t* __restrict__ out, int Mreal) {
  const int ms = blockIdx.x;                 // 16-row slab
  const int wave = threadIdx.x >> 6, lane = threadIdx.x & 63;
  const int KP = DIMX / 32;                  // 24
  int row = ms * 16 + (lane & 15);
  if (row >= Mreal) row = Mreal - 1;
  const int cb = (lane >> 4) * 8;
  const float* src = x + (size_t)row * DIMX + cb;
  bf16_t* dst = out + ((size_t)ms * KP) * 512 + lane * 8;
  for (int kp = wave; kp < KP; kp += 4) {
    const float4 a = *(const float4*)(src + kp * 32);
    const float4 b = *(const float4*)(src + kp * 32 + 4);
    bf16_t o8[8] = {(bf16_t)a.x, (bf16_t)a.y, (bf16_t)a.z, (bf16_t)a.w,
                    (bf16_t)b.x, (bf16_t)b.y, (bf16_t)b.z, (bf16_t)b.w};
    *(uint4*)(dst + (size_t)kp * 512) = *(uint4*)o8;
  }
}

// ---------------- batched transpose+cast of the 5 weight matrices ----------
// Output is panel-swizzled: elem (n,k) -> ((n>>4)*(Kd>>5) + (k>>5))*512 +
// ((n&15) + 16*((k>>3)&3))*8 + (k&7).
__global__ __launch_bounds__(256) void transpose_all(
    const float* __restrict__ Wq, const float* __restrict__ Wk,
    const float* __restrict__ Wv, const float* __restrict__ Wt,
    const float* __restrict__ Wf, bf16_t* __restrict__ WqkvT,
    bf16_t* __restrict__ WtT, bf16_t* __restrict__ WfT) {
  __shared__ float t[32][33];
  const int bid = blockIdx.x;
  const int mat = bid / 1728, tt = bid % 1728;
  const float* W; bf16_t* WT; int Kd, Nd, nt, kt;
  if (mat < 3) {
    Kd = DIMX; Nd = NCOL;
    W = (mat == 0) ? Wq : ((mat == 1) ? Wk : Wv);
    WT = WqkvT + (size_t)mat * NCOL * DIMX;  // 2304 % 16 == 0: concat-safe
    nt = tt % 72; kt = tt / 72;
  } else {
    Kd = NCOL; Nd = DIMX;
    W = (mat == 3) ? Wt : Wf;
    WT = (mat == 3) ? WtT : WfT;
    nt = tt % 24; kt = tt / 24;
  }
  const int bn = nt * 32, bk = kt * 32;
  const int KP = Kd >> 5;
  const int tx = threadIdx.x & 31, ty = threadIdx.x >> 5;  // 32 x 8
  #pragma unroll
  for (int i = 0; i < 32; i += 8)
    t[ty + i][tx] = W[(size_t)(bk + ty + i) * Nd + bn + tx];
  __syncthreads();
  const int k = bk + tx;  // fixed k per thread in the write loop
  #pragma unroll
  for (int i = 0; i < 32; i += 8) {
    const int n = bn + ty + i;
    const size_t off = ((size_t)(n >> 4) * KP + (k >> 5)) * 512 +
                       ((n & 15) + 16 * ((k >> 3) & 3)) * 8 + (k & 7);
    WT[off] = (bf16_t)t[tx][ty + i];
  }
}

// ---------------- bf16 MFMA GEMM: C = A @ BT^T + bias ----------------
// BT is ALWAYS panel-swizzled (preprocessed weights). A is swizzled when
// aSwz=1 (stage-1 activations) else row-major. Swizzled staging loads are
// fully contiguous 1024B wave reads (4 L2 transactions vs ~16 scattered).
// LDS layout / fragment reads / MFMA identical to prior rounds (verified).
__global__ __launch_bounds__(256) void gemm_mfma_bt(
    const bf16_t* __restrict__ A, const bf16_t* __restrict__ BT,
    const float* __restrict__ bias, void* __restrict__ C,
    int M, int N, int K, int MT, int NT, int GROUPM, int aSwz, int outBf16) {
  __shared__ bf16_t As[128 * 64];
  __shared__ bf16_t Bs[128 * 64];
  const int tid  = threadIdx.x;
  const int wave = tid >> 6, lane = tid & 63;

  const int pid   = blockIdx.x;
  const int npg   = GROUPM * NT;
  const int group = pid / npg;
  const int first_m = group * GROUPM;
  int gsm = MT - first_m; if (gsm > GROUPM) gsm = GROUPM;
  const int lpid  = pid % npg;
  const int m_tile = first_m + lpid % gsm;
  const int n_tile = lpid / gsm;
  const int row0 = m_tile * 128, col0 = n_tile * 128;

  const int KP = K >> 5;
  // B: swizzled panels; wave stages its two n-panels (rows col0+wave*32..+32)
  const bf16_t* Bpan = BT + ((size_t)(n_tile * 8 + wave * 2) * KP) * 512 + lane * 8;
  // A swizzled panels
  const bf16_t* Apan = A + ((size_t)(m_tile * 8 + wave * 2) * KP) * 512 + lane * 8;
  // A row-major fallback (per-lane scattered, as before)
  const int fr = lane & 15, kg = lane >> 4;
  int ra0 = row0 + wave * 32 + fr;
  int ra1 = ra0 + 16;
  if (ra0 >= M) ra0 = M - 1;
  if (ra1 >= M) ra1 = M - 1;
  const bf16_t* Ap0 = A + (size_t)ra0 * K + kg * 8;
  const bf16_t* Ap1 = A + (size_t)ra1 * K + kg * 8;

  const int la0 = (wave * 2 + 0) * 1024, la1 = (wave * 2 + 1) * 1024;
  const int mb = (wave & 1) * 4,  nb = (wave >> 1) * 4;   // 16-row panel idx
  const int m0 = (wave & 1) * 64, n0 = (wave >> 1) * 64;
  f32x4 acc[4][4] = {};

  for (int kk = 0; kk < K; kk += 64) {
    const int kp = kk >> 5;
    if (aSwz) {
      load_lds16(Apan + (size_t)kp * 512,            &As[la0]);
      load_lds16(Apan + (size_t)(kp + 1) * 512,      &As[la0 + 512]);
      load_lds16(Apan + (size_t)(KP + kp) * 512,     &As[la1]);
      load_lds16(Apan + (size_t)(KP + kp + 1) * 512, &As[la1 + 512]);
    } else {
      load_lds16(Ap0 + kk,      &As[la0]);
      load_lds16(Ap0 + kk + 32, &As[la0 + 512]);
      load_lds16(Ap1 + kk,      &As[la1]);
      load_lds16(Ap1 + kk + 32, &As[la1 + 512]);
    }
    load_lds16(Bpan + (size_t)kp * 512,            &Bs[la0]);
    load_lds16(Bpan + (size_t)(kp + 1) * 512,      &Bs[la0 + 512]);
    load_lds16(Bpan + (size_t)(KP + kp) * 512,     &Bs[la1]);
    load_lds16(Bpan + (size_t)(KP + kp + 1) * 512, &Bs[la1 + 512]);
    __syncthreads();

    #pragma unroll
    for (int h = 0; h < 2; ++h) {
      bf16x8 af[4], bfr[4];
      #pragma unroll
      for (int i = 0; i < 4; ++i) {
        af[i]  = *(const bf16x8*)&As[(mb + i) * 1024 + h * 512 + lane * 8];
        bfr[i] = *(const bf16x8*)&Bs[(nb + i) * 1024 + h * 512 + lane * 8];
      }
      #pragma unroll
      for (int i = 0; i < 4; ++i)
        #pragma unroll
        for (int j = 0; j < 4; ++j)
          acc[i][j] = __builtin_amdgcn_mfma_f32_16x16x32_bf16(
              af[i], bfr[j], acc[i][j], 0, 0, 0);
    }
    __syncthreads();
  }

  const int cc = lane & 15, cr4 = (lane >> 4) * 4;
  #pragma unroll
  for (int i = 0; i < 4; ++i) {
    #pragma unroll
    for (int j = 0; j < 4; ++j) {
      const int col = col0 + n0 + j * 16 + cc;
      const float bcol = bias[col];
      #pragma unroll
      for (int reg = 0; reg < 4; ++reg) {
        const int r = row0 + m0 + i * 16 + cr4 + reg;
        if (r < M) {
          const float v = acc[i][j][reg] + bcol;
          if (outBf16) ((bf16_t*)C)[(size_t)r * N + col] = (bf16_t)v;
          else         ((float*)C)[(size_t)r * N + col] = v;
        }
      }
    }
  }
}

// ---------------- xi0 scores via MFMA: S = RSCALE * Q2 @ K2^T per (b,h) ------
// grid (2, 2, 96). Q at QKV2 col 0, K at col 2*NCOL; row stride NS.
__global__ __launch_bounds__(256) void xi0_scores_mfma(
    const bf16_t* __restrict__ QKV2, float* __restrict__ Smat) {
  __shared__ bf16_t As[128 * 32];
  __shared__ bf16_t Bs[128 * 32];
  const int tid  = threadIdx.x;
  const int wave = tid >> 6, lane = tid & 63;
  const int row0 = blockIdx.x * 128, col0 = blockIdx.y * 128;
  const int bh = blockIdx.z;
  const int b = bh / H_, h = bh % H_;
  const bf16_t* Abase = QKV2 + (size_t)b * P1 * NS + h * D3;             // Q2
  const bf16_t* Bbase = QKV2 + (size_t)b * P1 * NS + 2 * NCOL + h * D3;  // K2

  const int fr = lane & 15, kg = lane >> 4;
  int ra0 = row0 + wave * 32 + fr;
  int ra1 = ra0 + 16;
  if (ra0 >= P1) ra0 = P1 - 1;
  if (ra1 >= P1) ra1 = P1 - 1;
  int cb0 = col0 + wave * 32 + fr;
  int cb1 = cb0 + 16;
  if (cb0 >= P1) cb0 = P1 - 1;
  if (cb1 >= P1) cb1 = P1 - 1;
  const bf16_t* Ap0 = Abase + (size_t)ra0 * NS + kg * 8;
  const bf16_t* Ap1 = Abase + (size_t)ra1 * NS + kg * 8;
  const bf16_t* Bp0 = Bbase + (size_t)cb0 * NS + kg * 8;
  const bf16_t* Bp1 = Bbase + (size_t)cb1 * NS + kg * 8;
  bf16_t* lA0 = &As[(wave * 2 + 0) * 512];
  bf16_t* lA1 = &As[(wave * 2 + 1) * 512];
  bf16_t* lB0 = &Bs[(wave * 2 + 0) * 512];
  bf16_t* lB1 = &Bs[(wave * 2 + 1) * 512];

  const int m0 = (wave & 1) * 64, n0 = (wave >> 1) * 64;
  const int mb = (wave & 1) * 4,  nb = (wave >> 1) * 4;
  f32x4 acc[4][4] = {};

  for (int k0 = 0; k0 < D3; k0 += 32) {
    load_lds16(Ap0 + k0, lA0);
    load_lds16(Ap1 + k0, lA1);
    load_lds16(Bp0 + k0, lB0);
    load_lds16(Bp1 + k0, lB1);
    __syncthreads();
    bf16x8 af[4], bfr[4];
    #pragma unroll
    for (int i = 0; i < 4; ++i) {
      af[i]  = *(const bf16x8*)&As[(mb + i) * 512 + lane * 8];
      bfr[i] = *(const bf16x8*)&Bs[(nb + i) * 512 + lane * 8];
    }
    #pragma unroll
    for (int i = 0; i < 4; ++i)
      #pragma unroll
      for (int j = 0; j < 4; ++j)
        acc[i][j] = __builtin_amdgcn_mfma_f32_16x16x32_bf16(
            af[i], bfr[j], acc[i][j], 0, 0, 0);
    __syncthreads();
  }

  float* S = Smat + (size_t)bh * P1 * P1;
  const int cc = lane & 15, cr4 = (lane >> 4) * 4;
  #pragma unroll
  for (int i = 0; i < 4; ++i)
    #pragma unroll
    for (int j = 0; j < 4; ++j) {
      const int col = col0 + n0 + j * 16 + cc;
      #pragma unroll
      for (int reg = 0; reg < 4; ++reg) {
        const int r = row0 + m0 + i * 16 + cr4 + reg;
        if (r < P1 && col < P1) S[(size_t)r * P1 + col] = acc[i][j][reg] * RSCALE;
      }
    }
}

// ---------------- xi0 finish: wave-per-row stats, colsum, PV ----------------
__global__ __launch_bounds__(256) void xi0_finish_kernel(
    const float* __restrict__ Smat, const bf16_t* __restrict__ QKV2,
    bf16_t* __restrict__ FULL9b) {
  const int bh = blockIdx.x;
  const int b = bh / H_, h = bh % H_;
  __shared__ float mrow[P1], inv_l[P1], g[P1];
  const float* S = Smat + (size_t)bh * P1 * P1;
  const int tid = threadIdx.x;
  const int wave = tid >> 6, lane = tid & 63;

  for (int r = wave; r < P1; r += 4) {
    const float* Sr = S + (size_t)r * P1;
    const float s0 = Sr[lane];
    const float s1 = Sr[64 + lane];
    const float s2 = Sr[128 + lane];
    const float s3 = (lane < 3) ? Sr[192 + lane] : -1e30f;
    float m = fmaxf(fmaxf(s0, s1), fmaxf(s2, s3));
    #pragma unroll
    for (int o = 1; o < 64; o <<= 1) m = fmaxf(m, __shfl_xor(m, o, 64));
    float e = expf(s0 - m) * ((lane == 0) ? 2.f : 1.f) + expf(s1 - m) +
              expf(s2 - m) + ((lane < 3) ? expf(s3 - m) : 0.f);
    #pragma unroll
    for (int o = 1; o < 64; o <<= 1) e += __shfl_xor(e, o, 64);
    if (lane == 0) {
      mrow[r] = m;
      inv_l[r] = ((r == 0) ? 2.f : 1.f) / e;
    }
  }
  __syncthreads();
  if (tid < P1) {
    float s = 0.f;
    for (int r = 0; r < P1; ++r)
      s += expf(S[(size_t)r * P1 + tid] - mrow[r]) * inv_l[r];
    g[tid] = s * ((tid == 0) ? 2.f : 1.f);
  }
  __syncthreads();
  if (tid < D3) {
    float acc = 0.f;
    const bf16_t* vbase = QKV2 + (size_t)b * P1 * NS + NCOL + h * D3 + tid;  // V2
    for (int k = 0; k < P1; ++k)
      acc = fmaf(g[k], (float)vbase[(size_t)k * NS], acc);
    FULL9b[((size_t)b * 9 + 1) * NCOL + h * D3 + tid] = (bf16_t)acc;
  }
}

// ---------------- cls attention, split over keys ----------------
// XQKV row layout: [q | k(Wk) | v(Wv)], stride NS.
__global__ __launch_bounds__(256) void cls_part_kernel(
    const bf16_t* __restrict__ XQKV, float* __restrict__ CLSP, int b0) {
  const int h  = blockIdx.x % H_;
  const int bl = blockIdx.x / H_;
  const int b  = b0 + bl;
  const int c  = blockIdx.y;
  const int t0 = c * CH;
  const int tend = (t0 + CH < SEQ) ? t0 + CH : SEQ;
  __shared__ float qs[D3];
  __shared__ float sc[CH];
  __shared__ float red[4];
  const int tid = threadIdx.x;

  const bf16_t* Qr = XQKV + (size_t)bl * SEQ * NS + h * D3;
  if (tid < 24) {
    const bf16x8 q8 = *(const bf16x8*)(Qr + tid * 8);
    #pragma unroll
    for (int m2 = 0; m2 < 8; ++m2) qs[tid * 8 + m2] = (float)q8[m2];
  }
  __syncthreads();

  float lmax = -1e30f;
  for (int t = t0 + tid; t < tend; t += 256) {
    const bf16_t* kr = XQKV + ((size_t)bl * SEQ + t) * NS + NCOL + h * D3;
    float acc = 0.f;
    #pragma unroll 3
    for (int d = 0; d < D3; d += 8) {
      const bf16x8 k8 = *(const bf16x8*)(kr + d);
      #pragma unroll
      for (int m2 = 0; m2 < 8; ++m2) acc = fmaf(qs[d + m2], (float)k8[m2], acc);
    }
    acc *= RSCALE;
    sc[t - t0] = acc;
    lmax = fmaxf(lmax, acc);
  }
  const float m = block_max256(lmax, red);
  float lsum = 0.f;
  for (int t = t0 + tid; t < tend; t += 256) {
    const float e = expf(sc[t - t0] - m);
    sc[t - t0] = e;
    lsum += e;
  }
  const float L = block_sum256(lsum, red);
  __syncthreads();

  float* P = CLSP + ((size_t)(b * H_ + h) * NCHUNK + c) * CLS_STRIDE;
  if (tid < D3) {
    float acc = 0.f;
    const bf16_t* vbase = XQKV + ((size_t)bl * SEQ + t0) * NS + 2 * NCOL + h * D3 + tid;
    for (int t = t0; t < tend; ++t)
      acc = fmaf(sc[t - t0], (float)vbase[(size_t)(t - t0) * NS], acc);
    P[tid] = acc;
  }
  if (tid == 192) P[192] = m;
  if (tid == 193) P[193] = L;
}

// ---------------- cls combine: merge NCHUNK partials ----------------
__global__ __launch_bounds__(256) void cls_combine_kernel(
    const float* __restrict__ CLSP, bf16_t* __restrict__ FULL9b) {
  const int bh = blockIdx.x;
  const int tid = threadIdx.x;
  const float* P = CLSP + (size_t)bh * NCHUNK * CLS_STRIDE;

  float M = -1e30f;
  #pragma unroll
  for (int c = 0; c < NCHUNK; ++c) M = fmaxf(M, P[c * CLS_STRIDE + 192]);
  float L = 0.f;
  float w[NCHUNK];
  #pragma unroll
  for (int c = 0; c < NCHUNK; ++c) {
    w[c] = expf(P[c * CLS_STRIDE + 192] - M);
    L += P[c * CLS_STRIDE + 193] * w[c];
  }
  if (tid < D3) {
    float acc = 0.f;
    #pragma unroll
    for (int c = 0; c < NCHUNK; ++c)
      acc = fmaf(w[c], P[c * CLS_STRIDE + tid], acc);
    const int b = bh / H_, h = bh % H_;
    FULL9b[((size_t)b * 9 + 0) * NCOL + h * D3 + tid] = (bf16_t)(acc / L);
  }
}

// ---------------- temporal attention, 4 patches (waves) per block ----------
// q col 0, k col 2*NCOL (Wv proj!), v col NCOL (Wk proj!).
__global__ __launch_bounds__(256) void temporal_kernel(
    const bf16_t* __restrict__ XQKV, bf16_t* __restrict__ T1U, int b0) {
  const int id = blockIdx.x;
  const int pg = id % PG4;
  const int h  = (id / PG4) % H_;
  const int bl = id / (PG4 * H_);
  const int b  = b0 + bl;
  const int wave = threadIdx.x >> 6, lane = threadIdx.x & 63;
  __shared__ float qs[4][8][196], ks[4][8][196];

  int pi = pg * 4 + wave;
  const bool act = (pi < P1);
  if (!act) pi = P1 - 1;

  #pragma unroll
  for (int i = 0; i < 6; ++i) {
    const int idx = lane + 64 * i;  // 0..383: [0,192) -> qs, [192,384) -> ks
    const int arr = idx / 192;
    const int c = idx % 192;        // chunk of 8 dims
    const int f = c / 24, d0 = (c % 24) * 8;
    const size_t base = ((size_t)bl * SEQ + (size_t)f * NP + pi + 2) * NS +
                        (arr ? 2 * NCOL : 0) + h * D3 + d0;
    const bf16x8 v8 = *(const bf16x8*)(XQKV + base);
    float* dst = arr ? &ks[wave][f][d0] : &qs[wave][f][d0];
    #pragma unroll
    for (int m2 = 0; m2 < 8; ++m2) dst[m2] = (float)v8[m2];
  }
  __syncthreads();

  const int f = lane >> 3, g = lane & 7;
  float s = 0.f;
  for (int d = 0; d < D3; d += 4) {
    const float4 a4 = *(const float4*)&qs[wave][f][d];
    const float4 b4 = *(const float4*)&ks[wave][g][d];
    s = fmaf(a4.x, b4.x, s); s = fmaf(a4.y, b4.y, s);
    s = fmaf(a4.z, b4.z, s); s = fmaf(a4.w, b4.w, s);
  }
  s *= RSCALE;

  float m = s;
  #pragma unroll
  for (int o = 1; o < 8; o <<= 1) m = fmaxf(m, __shfl_xor(m, o, 64));
  const float e = expf(s - m);
  float sum = e;
  #pragma unroll
  for (int o = 1; o < 8; o <<= 1) sum += __shfl_xor(sum, o, 64);
  float a = e / sum;
  #pragma unroll
  for (int o = 8; o < 64; o <<= 1) a += __shfl_xor(a, o, 64);  // column sums
  float wg[8];
  #pragma unroll
  for (int gg = 0; gg < 8; ++gg) wg[gg] = __shfl(a, gg, 64);

  if (act) {
    const size_t vrow = (size_t)bl * SEQ * NS + NCOL + h * D3;  // values: Wk proj
    #pragma unroll
    for (int i = 0; i < 3; ++i) {
      const int d = lane + 64 * i;
      float o = 0.f;
      #pragma unroll
      for (int gg = 0; gg < 8; ++gg) {
        const bf16_t vv = XQKV[vrow + ((size_t)gg * NP + pi + 2) * NS + d];
        o = fmaf(wg[gg], (float)vv, o);
      }
      T1U[((size_t)b * P1 + pi) * NCOL + h * D3 + d] = (bf16_t)o;
    }
  }
}

// ---------------- stage-2, xi = 1..7: 195(+dup row xi) queries over 8 keys ----
// QKV2 layout: [q2 | v2(Wk) | k2(Wv)], stride NS.
__global__ __launch_bounds__(256) void stage2_xi_kernel(
    const bf16_t* __restrict__ QKV2, bf16_t* __restrict__ FULL9b) {
  const int xi = 1 + blockIdx.x % 7;
  const int h  = (blockIdx.x / 7) % H_;
  const int b  = blockIdx.x / (7 * H_);
  __shared__ float Ks[8][196], Vs[8][196], Qs[32][196];
  __shared__ float Pp[32][8];
  const int tid = threadIdx.x;

  for (int idx = tid; idx < 192; idx += 256) {          // keys: col 2*NCOL
    const int k = idx / 24, d0 = (idx % 24) * 8;
    const bf16x8 v8 = *(const bf16x8*)(QKV2 + ((size_t)(b * P1 + xi + k)) * NS +
                                       2 * NCOL + h * D3 + d0);
    #pragma unroll
    for (int m2 = 0; m2 < 8; ++m2) Ks[k][d0 + m2] = (float)v8[m2];
  }
  for (int idx = tid; idx < 192; idx += 256) {          // values: col NCOL
    const int k = idx / 24, d0 = (idx % 24) * 8;
    const bf16x8 v8 = *(const bf16x8*)(QKV2 + ((size_t)(b * P1 + xi + k)) * NS +
                                       NCOL + h * D3 + d0);
    #pragma unroll
    for (int m2 = 0; m2 < 8; ++m2) Vs[k][d0 + m2] = (float)v8[m2];
  }

  float acc = 0.f;  // for d = tid (tid < 192)
  for (int c = 0; c < 7; ++c) {
    __syncthreads();
    for (int idx = tid; idx < 768; idx += 256) {        // 32 queries x 192 dims
      const int qr = idx / 24, d0 = (idx % 24) * 8;
      const int rq = c * 32 + qr;
      if (rq < P1) {
        const bf16x8 v8 = *(const bf16x8*)(QKV2 + ((size_t)(b * P1 + rq)) * NS +
                                           h * D3 + d0);
        #pragma unroll
        for (int m2 = 0; m2 < 8; ++m2) Qs[qr][d0 + m2] = (float)v8[m2];
      } else {
        #pragma unroll
        for (int m2 = 0; m2 < 8; ++m2) Qs[qr][d0 + m2] = 0.f;
      }
    }
    __syncthreads();
    const int grp = tid >> 3, k = tid & 7;
    float dot = 0.f;
    for (int d = 0; d < D3; d += 4) {
      const float4 a4 = *(const float4*)&Qs[grp][d];
      const float4 b4 = *(const float4*)&Ks[k][d];
      dot = fmaf(a4.x, b4.x, dot); dot = fmaf(a4.y, b4.y, dot);
      dot = fmaf(a4.z, b4.z, dot); dot = fmaf(a4.w, b4.w, dot);
    }
    dot *= RSCALE;
    float m = dot;
    #pragma unroll
    for (int o = 1; o < 8; o <<= 1) m = fmaxf(m, __shfl_xor(m, o, 64));
    const float e = expf(dot - m);
    float s = e;
    #pragma unroll
    for (int o = 1; o < 8; o <<= 1) s += __shfl_xor(s, o, 64);
    Pp[grp][k] = e / s;
    __syncthreads();
    if (tid < D3) {
      #pragma unroll 4
      for (int g2 = 0; g2 < 32; ++g2) {
        const int rq2 = c * 32 + g2;
        if (rq2 < P1) {
          const float mult = (rq2 == xi) ? 2.f : 1.f;
          float o = 0.f;
          #pragma unroll
          for (int kk = 0; kk < 8; ++kk) o = fmaf(Pp[g2][kk], Vs[kk][tid], o);
          acc = fmaf(mult, o, acc);
        }
      }
    }
  }
  if (tid < D3)
    FULL9b[((size_t)b * 9 + 1 + xi) * NCOL + h * D3 + tid] = (bf16_t)acc;
}

// ---------------- broadcast OUT9 -> full output ----------------
__global__ __launch_bounds__(256) void bcast_kernel(
    const float* __restrict__ OUT9, float* __restrict__ out) {
  const int idx = blockIdx.x * 256 + threadIdx.x;  // over float4s
  const int total = B_ * SEQ * (DIMX / 4);
  if (idx >= total) return;
  const int d4 = idx % (DIMX / 4);
  const int bs = idx / (DIMX / 4);
  const int s = bs % SEQ;
  const int b = bs / SEQ;
  const int row = (s == 0) ? 0 : 1 + ((s - 1) & 7);
  ((float4*)out)[idx] = ((const float4*)OUT9)[(size_t)(b * 9 + row) * (DIMX / 4) + d4];
}

// ---------------- launch ----------------
extern "C" void kernel_launch(void* const* d_in, const int* in_sizes, int n_in,
                              void* d_out, int out_size, void* d_ws, size_t ws_size,
                              hipStream_t stream) {
  const float* x  = (const float*)d_in[0];
  const float* Wq = (const float*)d_in[1];
  const float* bq = (const float*)d_in[2];
  const float* Wk = (const float*)d_in[3];
  const float* bk = (const float*)d_in[4];
  const float* Wv = (const float*)d_in[5];
  const float* bv = (const float*)d_in[6];
  const float* Wt = (const float*)d_in[7];
  const float* bt = (const float*)d_in[8];
  const float* Wf = (const float*)d_in[9];
  const float* bf = (const float*)d_in[10];
  float* out = (float*)d_out;
  (void)in_sizes; (void)n_in; (void)out_size;

  char* ws = (char*)d_ws;
  size_t off = 0;
  auto alloc_f32 = [&](size_t elems) {
    size_t a = (off + 63) & ~(size_t)63;
    off = a + elems * sizeof(float);
    return (float*)(ws + a);
  };
  auto alloc_bf16 = [&](size_t elems) {
    size_t a = (off + 63) & ~(size_t)63;
    off = a + elems * sizeof(bf16_t);
    return (bf16_t*)(ws + a);
  };

  bf16_t* T1Ub   = alloc_bf16((size_t)B_ * P1 * NCOL);
  bf16_t* TIUb   = alloc_bf16((size_t)B_ * P1 * DIMX);
  bf16_t* QKV2b  = alloc_bf16((size_t)B_ * P1 * NS);
  bf16_t* FULL9b = alloc_bf16((size_t)B_ * 9 * NCOL);
  float*  OUT9   = alloc_f32((size_t)B_ * 9 * DIMX);
  float*  Smat   = alloc_f32((size_t)B_ * H_ * P1 * P1);
  float*  CLSP   = alloc_f32((size_t)B_ * H_ * NCHUNK * CLS_STRIDE);
  float*  QKVbias= alloc_f32(NS);
  bf16_t* WqkvT  = alloc_bf16((size_t)3 * NCOL * DIMX);  // swizzled [WqT;WkT;WvT]
  bf16_t* WtT    = alloc_bf16((size_t)DIMX * NCOL);
  bf16_t* WfT    = alloc_bf16((size_t)DIMX * NCOL);

  // chunked stage-1 buffers (xb swizzled, padded to MT*128 rows)
  const size_t remain = (ws_size > off) ? (ws_size - off) : 0;
  int Bc = 8;
  while (Bc > 1 &&
         (size_t)(Bc * SEQ + 128) * (NS + DIMX) * sizeof(bf16_t) + 512 > remain)
    Bc >>= 1;
  const int MTmax = (Bc * SEQ + 127) / 128;
  bf16_t* XQKVb = alloc_bf16((size_t)Bc * SEQ * NS);
  bf16_t* xb    = alloc_bf16((size_t)MTmax * 128 * DIMX);

  // ---- weight transposes (swizzled) + fused bias
  transpose_all<<<dim3(1728 * 5), 256, 0, stream>>>(
      Wq, Wk, Wv, Wt, Wf, WqkvT, WtT, WfT);
  concat_bias_kernel<<<dim3((NS + 255) / 256), 256, 0, stream>>>(bq, bk, bv, QKVbias);

  // ---- stage 1 (chunked): swizzle-cast x, fused QKV GEMM, attn
  for (int b0 = 0; b0 < B_; b0 += Bc) {
    const int Mrows = Bc * SEQ;
    const int MT = (Mrows + 127) / 128, NT = NS / 128;
    cast_swizzle<<<dim3(MT * 8), 256, 0, stream>>>(
        x + (size_t)b0 * SEQ * DIMX, xb, Mrows);
    gemm_mfma_bt<<<dim3(MT * NT), 256, 0, stream>>>(
        xb, WqkvT, QKVbias, XQKVb, Mrows, NS, DIMX, MT, NT, 8, 1, 1);
    cls_part_kernel<<<dim3(Bc * H_, NCHUNK), 256, 0, stream>>>(XQKVb, CLSP, b0);
    temporal_kernel<<<dim3(Bc * H_ * PG4), 256, 0, stream>>>(XQKVb, T1Ub, b0);
  }
  cls_combine_kernel<<<dim3(B_ * H_), 256, 0, stream>>>(CLSP, FULL9b);

  // ---- ti = merge(t1u) @ Wt + bt  (bf16 out; A row-major)
  {
    const int MT = (B_ * P1 + 127) / 128, NT = DIMX / 128;
    gemm_mfma_bt<<<dim3(MT * NT), 256, 0, stream>>>(
        T1Ub, WtT, bt, TIUb, B_ * P1, DIMX, NCOL, MT, NT, 4, 0, 1);
  }
  // ---- fused stage-2 QKV: [q2 | v2(Wk) | k2(Wv)] = ti @ Wqkv
  {
    const int MT = (B_ * P1 + 127) / 128, NT = NS / 128;
    gemm_mfma_bt<<<dim3(MT * NT), 256, 0, stream>>>(
        TIUb, WqkvT, QKVbias, QKV2b, B_ * P1, NS, DIMX, MT, NT, 4, 0, 1);
  }

  // ---- stage-2 attentions -> FULL9 rows 1..8
  xi0_scores_mfma<<<dim3(2, 2, B_ * H_), 256, 0, stream>>>(QKV2b, Smat);
  xi0_finish_kernel<<<dim3(B_ * H_), 256, 0, stream>>>(Smat, QKV2b, FULL9b);
  stage2_xi_kernel<<<dim3(B_ * H_ * 7), 256, 0, stream>>>(QKV2b, FULL9b);

  // ---- final projection on the 9 unique rows per batch
  {
    const int MT = 1, NT = DIMX / 128;
    gemm_mfma_bt<<<dim3(MT * NT), 256, 0, stream>>>(
        FULL9b, WfT, bf, OUT9, B_ * 9, DIMX, NCOL, MT, NT, 1, 0, 0);
  }

  // ---- broadcast to the full (B, 1569, 768) output
  {
    const int total4 = B_ * SEQ * (DIMX / 4);
    bcast_kernel<<<dim3((total4 + 255) / 256), 256, 0, stream>>>(OUT9, out);
  }
}